// Round 11
// baseline (2460.836 us; speedup 1.0000x reference)
//
#include <hip/hip_runtime.h>
#include <hip/hip_bf16.h>
#include <math.h>

#define B 512
#define S 256
#define D 128
#define H 256
#define G4 1024
#define NS 32
#define NH 8
#define DH 32

typedef _Float16 half8 __attribute__((ext_vector_type(8)));
typedef _Float16 half4v __attribute__((ext_vector_type(4)));
typedef _Float16 half2v __attribute__((ext_vector_type(2)));
typedef float f32x4 __attribute__((ext_vector_type(4)));

__device__ __forceinline__ float sigm(float v) { return 1.f / (1.f + __expf(-v)); }
__device__ __forceinline__ float tanh_fast(float x) { float e = __expf(2.f * x); return 1.f - 2.f / (e + 1.f); }
__device__ __forceinline__ float cvtf(float v) { return v; }
__device__ __forceinline__ float cvtf(_Float16 v) { return (float)v; }

// ---------------- prep: fp16 weight slices + fp32 k-major transposes for tail ----------------
__global__ void prep_kernel(const float* __restrict__ s_wih, const float* __restrict__ s_whh,
                            const float* __restrict__ s_bih, const float* __restrict__ s_bhh,
                            const float* __restrict__ m_wih, const float* __restrict__ m_whh,
                            const float* __restrict__ m_bih, const float* __restrict__ m_bhh,
                            const float* __restrict__ stw, const float* __restrict__ mtw,
                            const float* __restrict__ in_w, const float* __restrict__ outp_w,
                            const float* __restrict__ w1, const float* __restrict__ w2,
                            _Float16* __restrict__ W16h, _Float16* __restrict__ W16l,
                            float* __restrict__ biasP, _Float16* __restrict__ trW16,
                            float* __restrict__ in_wT, float* __restrict__ outp_wT,
                            float* __restrict__ w1T, float* __restrict__ w2T)
{
    int tid = blockIdx.x * blockDim.x + threadIdx.x;
    int stride = gridDim.x * blockDim.x;
    for (int i = tid; i < 2 * 8 * 128 * 384; i += stride) {
        int k = i % 384; int n = (i / 384) % 128; int c = (i / (384 * 128)) % 8; int L = i / (384 * 128 * 8);
        int row = (n >> 5) * 256 + c * 32 + (n & 31);
        const float* wih = L ? m_wih : s_wih;
        const float* whh = L ? m_whh : s_whh;
        float v = (k < 128) ? wih[row * 128 + k] : whh[row * 256 + (k - 128)];
        W16h[i] = (_Float16)v;
    }
    for (int i = tid; i < 2 * 8 * 128 * 256; i += stride) {
        int k = i % 256; int n = (i / 256) % 128; int c = (i / (256 * 128)) % 8; int L = i / (256 * 128 * 8);
        int row = (n >> 5) * 256 + c * 32 + (n & 31);
        const float* whh = L ? m_whh : s_whh;
        float v = whh[row * 256 + k];
        _Float16 hi = (_Float16)v;
        W16l[i] = (_Float16)(v - (float)hi);
    }
    for (int i = tid; i < 2 * 8 * 128; i += stride) {
        int n = i % 128; int c = (i / 128) % 8; int L = i / (128 * 8);
        int row = (n >> 5) * 256 + c * 32 + (n & 31);
        biasP[i] = L ? (m_bih[row] + m_bhh[row]) : (s_bih[row] + s_bhh[row]);
    }
    for (int i = tid; i < 256 * 128; i += stride) {
        int k = i % 128, n = i / 128;
        trW16[i] = (_Float16)(n < 128 ? stw[n * 128 + k] : mtw[(n - 128) * 128 + k]);
    }
    for (int i = tid; i < H * 768; i += stride)  { int k = i / 768, n = i % 768;  in_wT[i]  = in_w[n * H + k]; }
    for (int i = tid; i < H * H; i += stride)    { int k = i / H,   n = i % H;    outp_wT[i]= outp_w[n * H + k]; }
    for (int i = tid; i < H * G4; i += stride)   { int k = i / G4,  n = i % G4;   w1T[i]    = w1[n * H + k]; }
    for (int i = tid; i < G4 * H; i += stride)   { int k2 = i / H,  n = i % H;    w2T[i]    = w2[n * G4 + k2]; }
}

// ---------------- xtr: xtr16[L][b][t][d] = fp16(tanh(x @ trW^T + trb)), MFMA ----------------
__global__ __launch_bounds__(256, 1) void xtr_kernel(const float* __restrict__ x,
        const _Float16* __restrict__ trW16,
        const float* __restrict__ stb, const float* __restrict__ mtb,
        _Float16* __restrict__ xtr16)
{
    const int b = blockIdx.x;
    const int tid = threadIdx.x;
    const int w = tid >> 6, l = tid & 63, l15 = l & 15, l4 = l >> 4;

    __shared__ _Float16 xa[128 * 128];

    half8 bw[4][4];
#pragma unroll
    for (int kk = 0; kk < 4; kk++)
#pragma unroll
        for (int ni = 0; ni < 4; ni++)
            bw[kk][ni] = *(const half8*)(trW16 + (w * 64 + ni * 16 + l15) * 128 + kk * 32 + l4 * 8);
    float tb[4];
#pragma unroll
    for (int ni = 0; ni < 4; ni++) { int d = w * 64 + ni * 16 + l15; tb[ni] = d < 128 ? stb[d] : mtb[d - 128]; }

    for (int h2 = 0; h2 < 2; ++h2) {
        {
            int trow = tid >> 1, seg = tid & 1;
            const float* src = x + ((size_t)b * S + h2 * 128 + trow) * 128 + seg * 64;
            int swz = (trow & 7) << 4;
#pragma unroll
            for (int q8 = 0; q8 < 8; q8++) {
                float4 f0 = *(const float4*)(src + q8 * 8);
                float4 f1 = *(const float4*)(src + q8 * 8 + 4);
                half8 hv = { (_Float16)f0.x, (_Float16)f0.y, (_Float16)f0.z, (_Float16)f0.w,
                             (_Float16)f1.x, (_Float16)f1.y, (_Float16)f1.z, (_Float16)f1.w };
                int byte = ((seg * 64 + q8 * 8) * 2) ^ swz;
                *(half8*)((char*)(xa + trow * 128) + byte) = hv;
            }
        }
        __syncthreads();
        for (int mt = 0; mt < 8; ++mt) {
            int row = mt * 16 + l15;
            int swz = (row & 7) << 4;
            half8 af[4];
#pragma unroll
            for (int kk = 0; kk < 4; kk++) {
                int byte = ((kk * 32 + l4 * 8) * 2) ^ swz;
                af[kk] = *(const half8*)((const char*)(xa + row * 128) + byte);
            }
            f32x4 acc[4];
#pragma unroll
            for (int ni = 0; ni < 4; ni++) acc[ni] = (f32x4){ tb[ni], tb[ni], tb[ni], tb[ni] };
#pragma unroll
            for (int kk = 0; kk < 4; kk++)
#pragma unroll
                for (int ni = 0; ni < 4; ni++)
                    acc[ni] = __builtin_amdgcn_mfma_f32_16x16x32_f16(af[kk], bw[kk][ni], acc[ni], 0, 0, 0);
#pragma unroll
            for (int ni = 0; ni < 4; ni++) {
                int d = w * 64 + ni * 16 + l15;
                int Ls = d >> 7, dl = d & 127;
#pragma unroll
                for (int r = 0; r < 4; r++) {
                    int t = h2 * 128 + mt * 16 + l4 * 4 + r;
                    xtr16[(((size_t)Ls * B + b) * S + t) * 128 + dl] = (_Float16)tanh_fast(acc[ni][r]);
                }
            }
        }
        __syncthreads();
    }
}

// ---------------- persistent MFMA LSTM: 1 chain/WG, grid 512 (2 WGs/CU overlap in HW) ----------
// bid = sC*64 + r ; r = L*32 + bt ; batch tile = bt*16..+15 ; WG owns gate cols sC*32*4 (128)
// Exchange: sc0sc1 stores to L3 + per-WAVE flags (vmcnt is per-wave; one store inst covers the
// wave's 64 lanes), so no barrier between store-drain and flag. 2 barriers/step total.
template<typename HT>
__global__ __launch_bounds__(256, 2) void lstm_mfma(
    const _Float16* __restrict__ W16h, const _Float16* __restrict__ W16l,
    const float* __restrict__ biasP,
    const _Float16* __restrict__ xtr16,
    HT* __restrict__ hs, _Float16* __restrict__ hG, unsigned int* __restrict__ flags)
{
    const int bid = blockIdx.x;
    const int sC = bid >> 6;           // 0..7
    const int r  = bid & 63;           // L*32 + bt
    const int L  = r >> 5;
    const int bt = r & 31;
    const int b0 = bt * 16;
    const int tid = threadIdx.x;
    const int w = tid >> 6, l = tid & 63, l15 = l & 15, l4 = l >> 4;

    __shared__ _Float16 Ah[16 * 384];   // [b][k]: k<128 xtr, k>=128 h hi; XOR-swz 16B units
    __shared__ _Float16 Al[16 * 256];   // h lo
    __shared__ float gl[16][132];

    for (int i = tid; i < 16 * 384 * 2 / 16; i += 256) ((int4*)Ah)[i] = make_int4(0, 0, 0, 0);
    for (int i = tid; i < 16 * 256 * 2 / 16; i += 256) ((int4*)Al)[i] = make_int4(0, 0, 0, 0);

    // resident weight fragments
    const size_t wbh = ((size_t)(L * 8 + sC) * 128) * 384;
    const size_t wbl = ((size_t)(L * 8 + sC) * 128) * 256;
    half8 bwh[12][2], bwlo[8][2];
#pragma unroll
    for (int kk = 0; kk < 12; kk++)
#pragma unroll
        for (int ni = 0; ni < 2; ni++)
            bwh[kk][ni] = *(const half8*)(W16h + wbh + (size_t)(w * 32 + ni * 16 + l15) * 384 + kk * 32 + l4 * 8);
#pragma unroll
    for (int kk = 0; kk < 8; kk++)
#pragma unroll
        for (int ni = 0; ni < 2; ni++)
            bwlo[kk][ni] = *(const half8*)(W16l + wbl + (size_t)(w * 32 + ni * 16 + l15) * 256 + kk * 32 + l4 * 8);
    float bn[2];
#pragma unroll
    for (int ni = 0; ni < 2; ni++) bn[ni] = biasP[(L * 8 + sC) * 128 + w * 32 + ni * 16 + l15];

    const int b16 = tid >> 4;          // 0..15 batch within tile
    const int seg = tid & 15;          // 16-half chunk / 2-unit column pair
    const int bswz = (b16 & 7) << 4;
    const int aswz = (l15 & 7) << 4;

    // stage xtr(t=0)
    {
        const _Float16* src = xtr16 + (((size_t)L * B + b0 + b16) * S + 0) * 128 + seg * 8;
        half8 v0 = *(const half8*)src;
        *(half8*)((char*)(Ah + b16 * 384) + ((seg * 16) ^ bswz)) = v0;
    }
    float cst[2] = { 0.f, 0.f };
    _Float16* hGr = hG + (size_t)r * 2 * 16 * 512;
    __syncthreads();

    for (int t = 0; t < S; ++t) {
        const int par = t & 1;
        const bool more = (t < S - 1);
        // prefetch next xtr tile early (drains during gates)
        half8 xp = {};
        if (more) {
            const _Float16* src = xtr16 + (((size_t)L * B + b0 + b16) * S + (t + 1)) * 128 + seg * 8;
            xp = *(const half8*)src;
        }
        // ---- gates ----
        f32x4 a0 = (f32x4){ bn[0], bn[0], bn[0], bn[0] };
        f32x4 a1 = (f32x4){ bn[1], bn[1], bn[1], bn[1] };
        const char* ahBase = (const char*)(Ah + l15 * 384);
        const char* alBase = (const char*)(Al + l15 * 256);
#pragma unroll
        for (int kk = 0; kk < 4; kk++) {
            half8 ah = *(const half8*)(ahBase + (((kk * 32 + l4 * 8) * 2) ^ aswz));
            a0 = __builtin_amdgcn_mfma_f32_16x16x32_f16(ah, bwh[kk][0], a0, 0, 0, 0);
            a1 = __builtin_amdgcn_mfma_f32_16x16x32_f16(ah, bwh[kk][1], a1, 0, 0, 0);
        }
#pragma unroll
        for (int kk = 4; kk < 12; kk++) {
            int jb = ((kk - 4) * 32 + l4 * 8) * 2;
            half8 ah = *(const half8*)(ahBase + 256 + (jb ^ aswz));
            half8 al = *(const half8*)(alBase + (jb ^ aswz));
            a0 = __builtin_amdgcn_mfma_f32_16x16x32_f16(ah, bwh[kk][0], a0, 0, 0, 0);
            a0 = __builtin_amdgcn_mfma_f32_16x16x32_f16(ah, bwlo[kk - 4][0], a0, 0, 0, 0);
            a0 = __builtin_amdgcn_mfma_f32_16x16x32_f16(al, bwh[kk][0], a0, 0, 0, 0);
            a1 = __builtin_amdgcn_mfma_f32_16x16x32_f16(ah, bwh[kk][1], a1, 0, 0, 0);
            a1 = __builtin_amdgcn_mfma_f32_16x16x32_f16(ah, bwlo[kk - 4][1], a1, 0, 0, 0);
            a1 = __builtin_amdgcn_mfma_f32_16x16x32_f16(al, bwh[kk][1], a1, 0, 0, 0);
        }
#pragma unroll
        for (int q = 0; q < 4; q++) {
            gl[l4 * 4 + q][w * 32 + l15] = a0[q];
            gl[l4 * 4 + q][w * 32 + 16 + l15] = a1[q];
        }
        __syncthreads();   // B1: gl visible, all MFMA A-reads done
        // ---- pointwise: batch b16, units j2..j2+1 (global col sC*32 + j2) ----
        {
            int j2 = seg * 2;
            float2 iv = *(const float2*)&gl[b16][0 + j2];
            float2 fv = *(const float2*)&gl[b16][32 + j2];
            float2 gv = *(const float2*)&gl[b16][64 + j2];
            float2 ov = *(const float2*)&gl[b16][96 + j2];
            float iq[2] = { iv.x, iv.y }, fq[2] = { fv.x, fv.y }, gq[2] = { gv.x, gv.y }, oq[2] = { ov.x, ov.y };
            float hv[2]; _Float16 hh[2], hl[2];
#pragma unroll
            for (int q = 0; q < 2; q++) {
                float cc = sigm(fq[q]) * cst[q] + sigm(iq[q]) * tanh_fast(gq[q]);
                cst[q] = cc;
                hv[q] = sigm(oq[q]) * tanh_fast(cc);
                hh[q] = (_Float16)hv[q];
                hl[q] = (_Float16)(hv[q] - (float)hh[q]);
            }
            if (more) {
                _Float16* dst = hGr + par * 16 * 512 + b16 * 512 + sC * 32 + j2;
                half2v phi = { hh[0], hh[1] };
                half2v plo = { hl[0], hl[1] };
                asm volatile("global_store_dword %0, %1, off sc0 sc1" :: "v"(dst), "v"(phi) : "memory");
                asm volatile("global_store_dword %0, %1, off sc0 sc1" :: "v"(dst + 256), "v"(plo) : "memory");
            }
            // hs store (plain, L2-ack; consumed by a later kernel)
            size_t hidx = (((size_t)L * B + b0 + b16) * S + t) * H + sC * 32 + j2;
            if constexpr (sizeof(HT) == 4) {
                *(float2*)((float*)hs + hidx) = make_float2(hv[0], hv[1]);
            } else {
                half2v ph = { hh[0], hh[1] };
                *(half2v*)((_Float16*)hs + hidx) = ph;
            }
        }
        if (more) {
            // per-WAVE publish: wave's exchange stores are at L3 after vmcnt(0)
            asm volatile("s_waitcnt vmcnt(0)" ::: "memory");
            if (l == 0) {
                unsigned int one = 1u;
                const unsigned int* fp = flags + (((unsigned)r * 256u + (unsigned)t) * 8u + (unsigned)sC) * 4u + (unsigned)w;
                asm volatile("global_store_dword %0, %1, off sc0 sc1" :: "v"(fp), "v"(one) : "memory");
            }
            // xtr -> LDS while flags/peer stores fly (xp drained by vmcnt above)
            *(half8*)((char*)(Ah + b16 * 384) + ((seg * 16) ^ bswz)) = xp;
            // poll my writer's wave flag: writer WG sC = seg>>1, writer wave = b16>>2 == my wave
            {
                const unsigned int* fp = flags + (((unsigned)r * 256u + (unsigned)t) * 8u + (unsigned)(seg >> 1)) * 4u + (unsigned)w;
                unsigned int v;
                while (true) {
                    asm volatile("global_load_dword %0, %1, off sc0 sc1\n\ts_waitcnt vmcnt(0)"
                                 : "=v"(v) : "v"(fp) : "memory");
                    if (v) break;
                    __builtin_amdgcn_s_sleep(1);
                }
            }
            // consume my 16-unit chunk (hi+lo)
            {
                const _Float16* srch = hGr + par * 16 * 512 + b16 * 512 + seg * 16;
                half8 vh[2], vl[2];
#pragma unroll
                for (int u = 0; u < 2; u++) {
                    asm volatile("global_load_dwordx4 %0, %1, off sc0 sc1" : "=v"(vh[u]) : "v"(srch + u * 8) : "memory");
                    asm volatile("global_load_dwordx4 %0, %1, off sc0 sc1" : "=v"(vl[u]) : "v"(srch + 256 + u * 8) : "memory");
                }
                asm volatile("s_waitcnt vmcnt(0)" ::: "memory");
                __builtin_amdgcn_sched_barrier(0);
#pragma unroll
                for (int u = 0; u < 2; u++) {
                    int jb = (seg * 16 + u * 8) * 2;
                    *(half8*)((char*)(Ah + b16 * 384) + 256 + (jb ^ bswz)) = vh[u];
                    *(half8*)((char*)(Al + b16 * 256) + (jb ^ bswz)) = vl[u];
                }
            }
            __syncthreads();   // B2: h + xtr staged for next step
        }
    }
}

// ---------------- attention context (coalesced pass-1) ----------------
template<typename HT>
__global__ __launch_bounds__(256) void attn_ctx_kernel(const HT* __restrict__ hs_s, const HT* __restrict__ hs_m,
                                                       float* __restrict__ ctx_s, float* __restrict__ ctx_m)
{
    const int b = blockIdx.x;
    const int L = blockIdx.y;
    const HT* hsb = (L ? hs_m : hs_s) + (size_t)b * S * H;
    float* ctx = (L ? ctx_m : ctx_s) + b * H;
    const int tid = threadIdx.x;
    const int wv = tid >> 6, l = tid & 63;

    __shared__ float hlast[H];
    __shared__ float score[S];
    __shared__ float dist[S];
    __shared__ float red[4];

    hlast[tid] = cvtf(hsb[(size_t)(S - 1) * H + tid]);
    __syncthreads();

    const int segl = l & 15;
    for (int it = 0; it < 16; ++it) {
        int row = it * 16 + wv * 4 + (l >> 4);
        float s = 0.f;
        if constexpr (sizeof(HT) == 2) {
            const half8* p = (const half8*)(hsb + (size_t)row * H + segl * 16);
#pragma unroll
            for (int u = 0; u < 2; u++) {
                half8 v = p[u];
#pragma unroll
                for (int j = 0; j < 8; j++) s = fmaf((float)v[j], hlast[segl * 16 + u * 8 + j], s);
            }
        } else {
            const float4* p = (const float4*)(hsb + (size_t)row * H + segl * 16);
#pragma unroll
            for (int u = 0; u < 4; u++) {
                float4 v = p[u];
                s = fmaf(v.x, hlast[segl * 16 + u * 4 + 0], s);
                s = fmaf(v.y, hlast[segl * 16 + u * 4 + 1], s);
                s = fmaf(v.z, hlast[segl * 16 + u * 4 + 2], s);
                s = fmaf(v.w, hlast[segl * 16 + u * 4 + 3], s);
            }
        }
        s += __shfl_xor(s, 1); s += __shfl_xor(s, 2); s += __shfl_xor(s, 4); s += __shfl_xor(s, 8);
        if (segl == 0) score[row] = s;
    }
    __syncthreads();

    float sct = score[tid];
    float v = sct;
    for (int o = 32; o > 0; o >>= 1) v += __shfl_down(v, o);
    if ((tid & 63) == 0) red[tid >> 6] = v;
    __syncthreads();
    float denom = red[0] + red[1] + red[2] + red[3];
    dist[tid] = sct / denom;
    __syncthreads();

    float acc = 0.f;
    for (int t = 0; t < S; ++t) acc = fmaf(dist[t], cvtf(hsb[(size_t)t * H + tid]), acc);
    ctx[tid] = acc;
}

// ---------------- tail (k-major transposed weights -> coalesced streams) ----------------
__global__ __launch_bounds__(256) void tail_kernel(
    const float* __restrict__ ctx_s, const float* __restrict__ ctx_m,
    const float* __restrict__ norm_w, const float* __restrict__ norm_b,
    const float* __restrict__ macro_w,
    const float* __restrict__ in_wT, const float* __restrict__ in_b,
    const float* __restrict__ outp_wT, const float* __restrict__ outp_b,
    const float* __restrict__ w1T, const float* __restrict__ b1,
    const float* __restrict__ w2T, const float* __restrict__ b2,
    const float* __restrict__ fw, const float* __restrict__ fb,
    float* __restrict__ out)
{
    const int b = blockIdx.x;
    const int tid = threadIdx.x;

    __shared__ float ml[NS][H];
    __shared__ float buf[NS][H];
    __shared__ float qh[NS][DH], kh[NS][DH], vh[NS][DH], sc[NS][NS];
    __shared__ float red[4];

    float cs = ctx_s[b * H + tid];
    float v = cs;
    for (int o = 32; o > 0; o >>= 1) v += __shfl_down(v, o);
    if ((tid & 63) == 0) red[tid >> 6] = v;
    __syncthreads();
    float mean = (red[0] + red[1] + red[2] + red[3]) * (1.f / H);
    float dv = cs - mean;
    __syncthreads();
    v = dv * dv;
    for (int o = 32; o > 0; o >>= 1) v += __shfl_down(v, o);
    if ((tid & 63) == 0) red[tid >> 6] = v;
    __syncthreads();
    float stdv = sqrtf((red[0] + red[1] + red[2] + red[3]) * (1.f / (H - 1))) + 1e-8f;
    float z = dv / stdv;
    float cm = ctx_m[b * H + tid];
    float mwv = macro_w[0];
    for (int n = 0; n < NS; ++n)
        ml[n][tid] = norm_w[n * H + tid] * z + norm_b[n * H + tid] + mwv * cm;
    __syncthreads();

    const int dloc = tid & 31;
    const int iset = tid >> 5;
    const float scale = 0.17677669529663687f;
    for (int h = 0; h < NH; ++h) {
        {
            int rq = h * DH + dloc;
            float aq[4], ak[4], av[4];
#pragma unroll
            for (int rr = 0; rr < 4; rr++) { aq[rr] = in_b[rq]; ak[rr] = in_b[H + rq]; av[rr] = in_b[2 * H + rq]; }
            for (int k = 0; k < H; ++k) {
                float wq = in_wT[k * 768 + rq];
                float wk = in_wT[k * 768 + 256 + rq];
                float wv = in_wT[k * 768 + 512 + rq];
#pragma unroll
                for (int rr = 0; rr < 4; rr++) {
                    float m = ml[iset + 8 * rr][k];
                    aq[rr] = fmaf(m, wq, aq[rr]); ak[rr] = fmaf(m, wk, ak[rr]); av[rr] = fmaf(m, wv, av[rr]);
                }
            }
#pragma unroll
            for (int rr = 0; rr < 4; rr++) { qh[iset + 8 * rr][dloc] = aq[rr]; kh[iset + 8 * rr][dloc] = ak[rr]; vh[iset + 8 * rr][dloc] = av[rr]; }
        }
        __syncthreads();
        {
            int i = tid >> 3;
            int j0 = (tid & 7) * 4;
            float a[4] = { 0.f, 0.f, 0.f, 0.f };
            for (int d = 0; d < DH; ++d) {
                float q = qh[i][d];
#pragma unroll
                for (int jj = 0; jj < 4; jj++) a[jj] = fmaf(q, kh[j0 + jj][d], a[jj]);
            }
#pragma unroll
            for (int jj = 0; jj < 4; jj++) sc[i][j0 + jj] = a[jj] * scale;
        }
        __syncthreads();
        if (tid < NS) {
            float mx = -1e30f;
            for (int j = 0; j < NS; j++) mx = fmaxf(mx, sc[tid][j]);
            float sm = 0.f, e[NS];
            for (int j = 0; j < NS; j++) { e[j] = __expf(sc[tid][j] - mx); sm += e[j]; }
            float inv = 1.f / sm;
            for (int j = 0; j < NS; j++) sc[tid][j] = e[j] * inv;
        }
        __syncthreads();
        {
            int i = tid >> 3;
            int d0 = (tid & 7) * 4;
            float a[4] = { 0.f, 0.f, 0.f, 0.f };
            for (int j = 0; j < NS; ++j) {
                float sv = sc[i][j];
#pragma unroll
                for (int dd = 0; dd < 4; dd++) a[dd] = fmaf(sv, vh[j][d0 + dd], a[dd]);
            }
#pragma unroll
            for (int dd = 0; dd < 4; dd++) buf[i][h * DH + d0 + dd] = a[dd];
        }
        __syncthreads();
    }

    {
        float acc32[NS];
        float ob = outp_b[tid];
#pragma unroll
        for (int t = 0; t < NS; t++) acc32[t] = ob;
        for (int k = 0; k < H; ++k) {
            float w = outp_wT[k * H + tid];
#pragma unroll
            for (int t = 0; t < NS; t++) acc32[t] = fmaf(buf[t][k], w, acc32[t]);
        }
#pragma unroll
        for (int t = 0; t < NS; t++) ml[t][tid] += acc32[t];
    }
    __syncthreads();

    float acc_o[NS];
    {
        float b2v = b2[tid];
#pragma unroll
        for (int t = 0; t < NS; t++) acc_o[t] = b2v;
    }
    for (int jc = 0; jc < 4; ++jc) {
        float hid[NS];
        {
            float b1v = b1[jc * H + tid];
#pragma unroll
            for (int t = 0; t < NS; t++) hid[t] = b1v;
            for (int k = 0; k < H; ++k) {
                float w = w1T[k * G4 + jc * H + tid];
#pragma unroll
                for (int t = 0; t < NS; t++) hid[t] = fmaf(ml[t][k], w, hid[t]);
            }
        }
        __syncthreads();
#pragma unroll
        for (int t = 0; t < NS; t++) buf[t][tid] = fmaxf(hid[t], 0.f);
        __syncthreads();
        for (int k = 0; k < H; ++k) {
            float w = w2T[(jc * H + k) * H + tid];
#pragma unroll
            for (int t = 0; t < NS; t++) acc_o[t] = fmaf(buf[t][k], w, acc_o[t]);
        }
        __syncthreads();
    }

    float p = 0.f;
#pragma unroll
    for (int t = 0; t < NS; t++) p += tanhf(ml[t][tid] + acc_o[t]);
    p *= (1.f / NS);
    v = p * fw[tid];
    for (int o = 32; o > 0; o >>= 1) v += __shfl_down(v, o);
    if ((tid & 63) == 0) red[tid >> 6] = v;
    __syncthreads();
    if (tid == 0) out[b] = red[0] + red[1] + red[2] + red[3] + fb[0];
}

// ---------------- host ----------------
extern "C" void kernel_launch(void* const* d_in, const int* in_sizes, int n_in,
                              void* d_out, int out_size, void* d_ws, size_t ws_size,
                              hipStream_t stream) {
    const float* x      = (const float*)d_in[0];
    const float* stw    = (const float*)d_in[1];
    const float* stb    = (const float*)d_in[2];
    const float* mtw    = (const float*)d_in[3];
    const float* mtb    = (const float*)d_in[4];
    const float* s_wih  = (const float*)d_in[5];
    const float* s_whh  = (const float*)d_in[6];
    const float* s_bih  = (const float*)d_in[7];
    const float* s_bhh  = (const float*)d_in[8];
    const float* m_wih  = (const float*)d_in[9];
    const float* m_whh  = (const float*)d_in[10];
    const float* m_bih  = (const float*)d_in[11];
    const float* m_bhh  = (const float*)d_in[12];
    const float* norm_w = (const float*)d_in[13];
    const float* norm_b = (const float*)d_in[14];
    const float* macro_w= (const float*)d_in[15];
    const float* in_w   = (const float*)d_in[16];
    const float* in_b   = (const float*)d_in[17];
    const float* outp_w = (const float*)d_in[18];
    const float* outp_b = (const float*)d_in[19];
    const float* w1     = (const float*)d_in[20];
    const float* b1     = (const float*)d_in[21];
    const float* w2     = (const float*)d_in[22];
    const float* b2     = (const float*)d_in[23];
    const float* fw     = (const float*)d_in[24];
    const float* fb     = (const float*)d_in[25];
    float* out = (float*)d_out;

    // workspace layout (256B-aligned blocks)
    size_t off = 0;
    auto alloc = [&](size_t bytes) { char* q = (char*)d_ws + off; off += (bytes + 255) & ~(size_t)255; return q; };
    _Float16* W16h  = (_Float16*)alloc((size_t)2 * 8 * 128 * 384 * 2);
    _Float16* W16l  = (_Float16*)alloc((size_t)2 * 8 * 128 * 256 * 2);
    float*    biasP = (float*)alloc((size_t)2 * 8 * 128 * 4);
    _Float16* trW16 = (_Float16*)alloc((size_t)256 * 128 * 2);
    _Float16* hG    = (_Float16*)alloc((size_t)64 * 2 * 16 * 512 * 2);              // 2 MB
    unsigned int* flags = (unsigned int*)alloc((size_t)64 * 256 * 8 * 4 * 4);       // 2 MB
    float*    ctx_s = (float*)alloc((size_t)B * H * 4);
    float*    ctx_m = (float*)alloc((size_t)B * H * 4);
    float*    in_wT = (float*)alloc((size_t)H * 768 * 4);
    float*    outp_wT = (float*)alloc((size_t)H * H * 4);
    float*    w1T   = (float*)alloc((size_t)H * G4 * 4);
    float*    w2T   = (float*)alloc((size_t)G4 * H * 4);
    _Float16* xtr16 = (_Float16*)alloc((size_t)2 * B * S * 128 * 2);                // 64 MiB
    size_t off_before_hs = off;
    const size_t hs_elems = (size_t)2 * B * S * H;
    const size_t need_full = off_before_hs + hs_elems * sizeof(float) + (1u << 20);
    const bool f32hs = ws_size >= need_full;

    prep_kernel<<<128, 256, 0, stream>>>(s_wih, s_whh, s_bih, s_bhh,
                                         m_wih, m_whh, m_bih, m_bhh,
                                         stw, mtw, in_w, outp_w, w1, w2,
                                         W16h, W16l, biasP, trW16,
                                         in_wT, outp_wT, w1T, w2T);
    xtr_kernel<<<B, 256, 0, stream>>>(x, trW16, stb, mtb, xtr16);
    (void)hipMemsetAsync(flags, 0, (size_t)64 * 256 * 8 * 4 * 4, stream);

    if (f32hs) {
        float* hs = (float*)alloc(hs_elems * sizeof(float));
        lstm_mfma<float><<<512, 256, 0, stream>>>(W16h, W16l, biasP, xtr16, hs, hG, flags);
        attn_ctx_kernel<float><<<dim3(B, 2), 256, 0, stream>>>(hs, hs + hs_elems / 2, ctx_s, ctx_m);
    } else {
        _Float16* hs = (_Float16*)alloc(hs_elems * sizeof(_Float16));
        lstm_mfma<_Float16><<<512, 256, 0, stream>>>(W16h, W16l, biasP, xtr16, hs, hG, flags);
        attn_ctx_kernel<_Float16><<<dim3(B, 2), 256, 0, stream>>>(hs, hs + hs_elems / 2, ctx_s, ctx_m);
    }

    tail_kernel<<<B, 256, 0, stream>>>(ctx_s, ctx_m,
                                       norm_w, norm_b, macro_w,
                                       in_wT, in_b, outp_wT, outp_b,
                                       w1T, b1, w2T, b2, fw, fb, out);
}

// Round 12
// 2247.000 us; speedup vs baseline: 1.0952x; 1.0952x over previous
//
#include <hip/hip_runtime.h>
#include <hip/hip_bf16.h>
#include <math.h>

#define B 512
#define S 256
#define D 128
#define H 256
#define G4 1024
#define NS 32
#define NH 8
#define DH 32

typedef _Float16 half8 __attribute__((ext_vector_type(8)));
typedef _Float16 half4v __attribute__((ext_vector_type(4)));
typedef _Float16 half2v __attribute__((ext_vector_type(2)));
typedef float f32x4 __attribute__((ext_vector_type(4)));

__device__ __forceinline__ float sigm(float v) { return 1.f / (1.f + __expf(-v)); }
__device__ __forceinline__ float tanh_fast(float x) { float e = __expf(2.f * x); return 1.f - 2.f / (e + 1.f); }
__device__ __forceinline__ float cvtf(float v) { return v; }
__device__ __forceinline__ float cvtf(_Float16 v) { return (float)v; }

// ---------------- prep ----------------
__global__ void prep_kernel(const float* __restrict__ s_wih, const float* __restrict__ s_whh,
                            const float* __restrict__ s_bih, const float* __restrict__ s_bhh,
                            const float* __restrict__ m_wih, const float* __restrict__ m_whh,
                            const float* __restrict__ m_bih, const float* __restrict__ m_bhh,
                            const float* __restrict__ stw, const float* __restrict__ mtw,
                            const float* __restrict__ in_w, const float* __restrict__ outp_w,
                            const float* __restrict__ w1, const float* __restrict__ w2,
                            _Float16* __restrict__ W16h, _Float16* __restrict__ W16l,
                            float* __restrict__ biasP, _Float16* __restrict__ trW16,
                            float* __restrict__ in_wT, float* __restrict__ outp_wT,
                            float* __restrict__ w1T, float* __restrict__ w2T)
{
    int tid = blockIdx.x * blockDim.x + threadIdx.x;
    int stride = gridDim.x * blockDim.x;
    for (int i = tid; i < 2 * 8 * 128 * 384; i += stride) {
        int k = i % 384; int n = (i / 384) % 128; int c = (i / (384 * 128)) % 8; int L = i / (384 * 128 * 8);
        int row = (n >> 5) * 256 + c * 32 + (n & 31);
        const float* wih = L ? m_wih : s_wih;
        const float* whh = L ? m_whh : s_whh;
        float v = (k < 128) ? wih[row * 128 + k] : whh[row * 256 + (k - 128)];
        W16h[i] = (_Float16)v;
    }
    for (int i = tid; i < 2 * 8 * 128 * 256; i += stride) {
        int k = i % 256; int n = (i / 256) % 128; int c = (i / (256 * 128)) % 8; int L = i / (256 * 128 * 8);
        int row = (n >> 5) * 256 + c * 32 + (n & 31);
        const float* whh = L ? m_whh : s_whh;
        float v = whh[row * 256 + k];
        _Float16 hi = (_Float16)v;
        W16l[i] = (_Float16)(v - (float)hi);
    }
    for (int i = tid; i < 2 * 8 * 128; i += stride) {
        int n = i % 128; int c = (i / 128) % 8; int L = i / (128 * 8);
        int row = (n >> 5) * 256 + c * 32 + (n & 31);
        biasP[i] = L ? (m_bih[row] + m_bhh[row]) : (s_bih[row] + s_bhh[row]);
    }
    for (int i = tid; i < 256 * 128; i += stride) {
        int k = i % 128, n = i / 128;
        trW16[i] = (_Float16)(n < 128 ? stw[n * 128 + k] : mtw[(n - 128) * 128 + k]);
    }
    for (int i = tid; i < H * 768; i += stride)  { int k = i / 768, n = i % 768;  in_wT[i]  = in_w[n * H + k]; }
    for (int i = tid; i < H * H; i += stride)    { int k = i / H,   n = i % H;    outp_wT[i]= outp_w[n * H + k]; }
    for (int i = tid; i < H * G4; i += stride)   { int k = i / G4,  n = i % G4;   w1T[i]    = w1[n * H + k]; }
    for (int i = tid; i < G4 * H; i += stride)   { int k2 = i / H,  n = i % H;    w2T[i]    = w2[n * G4 + k2]; }
}

// ---------------- xtr ----------------
__global__ __launch_bounds__(256, 1) void xtr_kernel(const float* __restrict__ x,
        const _Float16* __restrict__ trW16,
        const float* __restrict__ stb, const float* __restrict__ mtb,
        _Float16* __restrict__ xtr16)
{
    const int b = blockIdx.x;
    const int tid = threadIdx.x;
    const int w = tid >> 6, l = tid & 63, l15 = l & 15, l4 = l >> 4;

    __shared__ _Float16 xa[128 * 128];

    half8 bw[4][4];
#pragma unroll
    for (int kk = 0; kk < 4; kk++)
#pragma unroll
        for (int ni = 0; ni < 4; ni++)
            bw[kk][ni] = *(const half8*)(trW16 + (w * 64 + ni * 16 + l15) * 128 + kk * 32 + l4 * 8);
    float tb[4];
#pragma unroll
    for (int ni = 0; ni < 4; ni++) { int d = w * 64 + ni * 16 + l15; tb[ni] = d < 128 ? stb[d] : mtb[d - 128]; }

    for (int h2 = 0; h2 < 2; ++h2) {
        {
            int trow = tid >> 1, seg = tid & 1;
            const float* src = x + ((size_t)b * S + h2 * 128 + trow) * 128 + seg * 64;
            int swz = (trow & 7) << 4;
#pragma unroll
            for (int q8 = 0; q8 < 8; q8++) {
                float4 f0 = *(const float4*)(src + q8 * 8);
                float4 f1 = *(const float4*)(src + q8 * 8 + 4);
                half8 hv = { (_Float16)f0.x, (_Float16)f0.y, (_Float16)f0.z, (_Float16)f0.w,
                             (_Float16)f1.x, (_Float16)f1.y, (_Float16)f1.z, (_Float16)f1.w };
                int byte = ((seg * 64 + q8 * 8) * 2) ^ swz;
                *(half8*)((char*)(xa + trow * 128) + byte) = hv;
            }
        }
        __syncthreads();
        for (int mt = 0; mt < 8; ++mt) {
            int row = mt * 16 + l15;
            int swz = (row & 7) << 4;
            half8 af[4];
#pragma unroll
            for (int kk = 0; kk < 4; kk++) {
                int byte = ((kk * 32 + l4 * 8) * 2) ^ swz;
                af[kk] = *(const half8*)((const char*)(xa + row * 128) + byte);
            }
            f32x4 acc[4];
#pragma unroll
            for (int ni = 0; ni < 4; ni++) acc[ni] = (f32x4){ tb[ni], tb[ni], tb[ni], tb[ni] };
#pragma unroll
            for (int kk = 0; kk < 4; kk++)
#pragma unroll
                for (int ni = 0; ni < 4; ni++)
                    acc[ni] = __builtin_amdgcn_mfma_f32_16x16x32_f16(af[kk], bw[kk][ni], acc[ni], 0, 0, 0);
#pragma unroll
            for (int ni = 0; ni < 4; ni++) {
                int d = w * 64 + ni * 16 + l15;
                int Ls = d >> 7, dl = d & 127;
#pragma unroll
                for (int r = 0; r < 4; r++) {
                    int t = h2 * 128 + mt * 16 + l4 * 4 + r;
                    xtr16[(((size_t)Ls * B + b) * S + t) * 128 + dl] = (_Float16)tanh_fast(acc[ni][r]);
                }
            }
        }
        __syncthreads();
    }
}

// ---------------- persistent MFMA LSTM: dual chain, counted-vmcnt pipeline ----------------
// grid 256: bid = sC*32 + r ; r = L*16 + btp ; chain c batches = btp*32 + c*16 .. +15
// Schedule: gatesA | pwA(stores issue) | gatesB (A-stores fly) | pwB | vmcnt(3) flagA |
//           vmcnt(1) flagB | xtr issue | pollA consumeA pollB consumeB | vmcnt(0) | LDS | bar
// ALL loop VMEM is inline asm so compiler can't inject its own waitcnt; barriers are raw
// s_barrier with explicit lgkmcnt(0) (no compiler vmcnt(0) drain).
#define LSTM_GATES(c)                                                                   \
    {                                                                                   \
        f32x4 a0 = (f32x4){ bn[0], bn[0], bn[0], bn[0] };                               \
        f32x4 a1 = (f32x4){ bn[1], bn[1], bn[1], bn[1] };                               \
        const char* ahBase = (const char*)(&Ah[c][0] + l15 * 384);                      \
        const char* alBase = (const char*)(&Al[c][0] + l15 * 256);                      \
        _Pragma("unroll")                                                               \
        for (int kk = 0; kk < 4; kk++) {                                                \
            half8 ah = *(const half8*)(ahBase + (((kk * 32 + l4 * 8) * 2) ^ aswz));     \
            a0 = __builtin_amdgcn_mfma_f32_16x16x32_f16(ah, bwh[kk][0], a0, 0, 0, 0);   \
            a1 = __builtin_amdgcn_mfma_f32_16x16x32_f16(ah, bwh[kk][1], a1, 0, 0, 0);   \
        }                                                                               \
        _Pragma("unroll")                                                               \
        for (int kk = 4; kk < 12; kk++) {                                               \
            int jb = ((kk - 4) * 32 + l4 * 8) * 2;                                      \
            half8 ah = *(const half8*)(ahBase + 256 + (jb ^ aswz));                     \
            half8 al = *(const half8*)(alBase + (jb ^ aswz));                           \
            a0 = __builtin_amdgcn_mfma_f32_16x16x32_f16(ah, bwh[kk][0], a0, 0, 0, 0);   \
            a0 = __builtin_amdgcn_mfma_f32_16x16x32_f16(ah, bwlo[kk - 4][0], a0, 0, 0, 0); \
            a0 = __builtin_amdgcn_mfma_f32_16x16x32_f16(al, bwh[kk][0], a0, 0, 0, 0);   \
            a1 = __builtin_amdgcn_mfma_f32_16x16x32_f16(ah, bwh[kk][1], a1, 0, 0, 0);   \
            a1 = __builtin_amdgcn_mfma_f32_16x16x32_f16(ah, bwlo[kk - 4][1], a1, 0, 0, 0); \
            a1 = __builtin_amdgcn_mfma_f32_16x16x32_f16(al, bwh[kk][1], a1, 0, 0, 0);   \
        }                                                                               \
        _Pragma("unroll")                                                               \
        for (int q = 0; q < 4; q++) {                                                   \
            gl[c][l4 * 4 + q][w * 32 + l15] = a0[q];                                    \
            gl[c][l4 * 4 + q][w * 32 + 16 + l15] = a1[q];                               \
        }                                                                               \
    }

// pw: exch stores (2) then hs store (1) -> 3 asm VMEM per chain, FIFO counted
#define LSTM_PW(c)                                                                      \
    {                                                                                   \
        int j2 = seg * 2;                                                               \
        float2 iv = *(const float2*)&gl[c][b16][0 + j2];                                \
        float2 fv = *(const float2*)&gl[c][b16][32 + j2];                               \
        float2 gv = *(const float2*)&gl[c][b16][64 + j2];                               \
        float2 ov = *(const float2*)&gl[c][b16][96 + j2];                               \
        float iq[2] = { iv.x, iv.y }, fq[2] = { fv.x, fv.y };                           \
        float gq[2] = { gv.x, gv.y }, oq[2] = { ov.x, ov.y };                           \
        float hv[2]; _Float16 hh[2], hl[2];                                             \
        _Pragma("unroll")                                                               \
        for (int q = 0; q < 2; q++) {                                                   \
            float cc = sigm(fq[q]) * cst[c][q] + sigm(iq[q]) * tanh_fast(gq[q]);        \
            cst[c][q] = cc;                                                             \
            hv[q] = sigm(oq[q]) * tanh_fast(cc);                                        \
            hh[q] = (_Float16)hv[q];                                                    \
            hl[q] = (_Float16)(hv[q] - (float)hh[q]);                                   \
        }                                                                               \
        if (more) {                                                                     \
            _Float16* dst = hG + ((size_t)(r * 2 + (c)) * 2 + par) * 16 * 512 + b16 * 512 + sC * 32 + j2; \
            half2v phi = { hh[0], hh[1] };                                              \
            half2v plo = { hl[0], hl[1] };                                              \
            asm volatile("global_store_dword %0, %1, off sc0 sc1" :: "v"(dst), "v"(phi) : "memory"); \
            asm volatile("global_store_dword %0, %1, off sc0 sc1" :: "v"(dst + 256), "v"(plo) : "memory"); \
        }                                                                               \
        size_t hidx = (((size_t)L * B + b0 + (c) * 16 + b16) * S + t) * H + sC * 32 + j2; \
        if constexpr (sizeof(HT) == 4) {                                                \
            float2 hv2 = make_float2(hv[0], hv[1]);                                     \
            asm volatile("global_store_dwordx2 %0, %1, off" :: "v"((float*)hs + hidx), "v"(hv2) : "memory"); \
        } else {                                                                        \
            half2v ph = { hh[0], hh[1] };                                               \
            asm volatile("global_store_dword %0, %1, off" :: "v"((_Float16*)hs + hidx), "v"(ph) : "memory"); \
        }                                                                               \
    }

template<typename HT>
__global__ __launch_bounds__(256, 1) void lstm_mfma(
    const _Float16* __restrict__ W16h, const _Float16* __restrict__ W16l,
    const float* __restrict__ biasP,
    const _Float16* __restrict__ xtr16,
    HT* __restrict__ hs, _Float16* __restrict__ hG, unsigned int* __restrict__ flags)
{
    const int bid = blockIdx.x;
    const int sC = bid >> 5;           // 0..7 gate-column chunk
    const int r  = bid & 31;           // L*16 + btp
    const int L  = r >> 4;
    const int btp = r & 15;
    const int b0 = btp * 32;
    const int tid = threadIdx.x;
    const int w = tid >> 6, l = tid & 63, l15 = l & 15, l4 = l >> 4;

    __shared__ _Float16 Ah[2][16 * 384];
    __shared__ _Float16 Al[2][16 * 256];
    __shared__ float gl[2][16][132];

    for (int i = tid; i < 2 * 16 * 384 * 2 / 16; i += 256) ((int4*)&Ah[0][0])[i] = make_int4(0, 0, 0, 0);
    for (int i = tid; i < 2 * 16 * 256 * 2 / 16; i += 256) ((int4*)&Al[0][0])[i] = make_int4(0, 0, 0, 0);

    const size_t wbh = ((size_t)(L * 8 + sC) * 128) * 384;
    const size_t wbl = ((size_t)(L * 8 + sC) * 128) * 256;
    half8 bwh[12][2], bwlo[8][2];
#pragma unroll
    for (int kk = 0; kk < 12; kk++)
#pragma unroll
        for (int ni = 0; ni < 2; ni++)
            bwh[kk][ni] = *(const half8*)(W16h + wbh + (size_t)(w * 32 + ni * 16 + l15) * 384 + kk * 32 + l4 * 8);
#pragma unroll
    for (int kk = 0; kk < 8; kk++)
#pragma unroll
        for (int ni = 0; ni < 2; ni++)
            bwlo[kk][ni] = *(const half8*)(W16l + wbl + (size_t)(w * 32 + ni * 16 + l15) * 256 + kk * 32 + l4 * 8);
    float bn[2];
#pragma unroll
    for (int ni = 0; ni < 2; ni++) bn[ni] = biasP[(L * 8 + sC) * 128 + w * 32 + ni * 16 + l15];

    const int b16 = tid >> 4;
    const int seg = tid & 15;
    const int bswz = (b16 & 7) << 4;
    const int aswz = (l15 & 7) << 4;

#pragma unroll
    for (int c = 0; c < 2; c++) {
        const _Float16* src = xtr16 + (((size_t)L * B + b0 + c * 16 + b16) * S + 0) * 128 + seg * 8;
        half8 v0 = *(const half8*)src;
        *(half8*)((char*)(&Ah[c][0] + b16 * 384) + ((seg * 16) ^ bswz)) = v0;
    }
    float cst[2][2] = { { 0.f, 0.f }, { 0.f, 0.f } };
    half8 xp[2];
    half8 cvh[2][2], cvl[2][2];
    __syncthreads();

    for (int t = 0; t < S; ++t) {
        const int par = t & 1;
        const bool more = (t < S - 1);

        LSTM_GATES(0)
        asm volatile("s_waitcnt lgkmcnt(0)" ::: "memory");
        __builtin_amdgcn_s_barrier();                       // B1: gl[0] visible

        LSTM_PW(0)                                          // exchA(2)+hsA(1) issued
        LSTM_GATES(1)                                       // A's stores fly under MFMA
        asm volatile("s_waitcnt lgkmcnt(0)" ::: "memory");
        __builtin_amdgcn_s_barrier();                       // B2: gl[1] visible

        LSTM_PW(1)                                          // exchB(2)+hsB(1) issued

        if (more) {
            asm volatile("s_waitcnt vmcnt(3)" ::: "memory");   // A fully drained
            if (l == 0) {
                unsigned int one = 1u;
                const unsigned int* fpA = flags + ((((size_t)r * 256 + t) * 2 + 0) * 8 + sC) * 4 + w;
                asm volatile("global_store_dword %0, %1, off sc0 sc1" :: "v"(fpA), "v"(one) : "memory");
            }
            asm volatile("s_waitcnt vmcnt(1)" ::: "memory");   // B drained (flagA may fly)
            if (l == 0) {
                unsigned int one = 1u;
                const unsigned int* fpB = flags + ((((size_t)r * 256 + t) * 2 + 1) * 8 + sC) * 4 + w;
                asm volatile("global_store_dword %0, %1, off sc0 sc1" :: "v"(fpB), "v"(one) : "memory");
            }
            // xtr prefetch for next step (drains under polls)
#pragma unroll
            for (int c = 0; c < 2; c++) {
                const _Float16* src = xtr16 + (((size_t)L * B + b0 + c * 16 + b16) * S + (t + 1)) * 128 + seg * 8;
                asm volatile("global_load_dwordx4 %0, %1, off" : "=v"(xp[c]) : "v"(src) : "memory");
            }
            // poll + consume, chain 0 then chain 1
#pragma unroll
            for (int c = 0; c < 2; c++) {
                {
                    const unsigned int* fp = flags + ((((size_t)r * 256 + t) * 2 + c) * 8 + (seg >> 1)) * 4 + w;
                    unsigned int v;
                    while (true) {
                        asm volatile("global_load_dword %0, %1, off sc0 sc1\n\ts_waitcnt vmcnt(0)"
                                     : "=v"(v) : "v"(fp) : "memory");
                        if (v) break;
                        __builtin_amdgcn_s_sleep(1);
                    }
                }
                {
                    const _Float16* srch = hG + ((size_t)(r * 2 + c) * 2 + par) * 16 * 512 + b16 * 512 + seg * 16;
#pragma unroll
                    for (int u = 0; u < 2; u++) {
                        asm volatile("global_load_dwordx4 %0, %1, off sc0 sc1" : "=v"(cvh[c][u]) : "v"(srch + u * 8) : "memory");
                        asm volatile("global_load_dwordx4 %0, %1, off sc0 sc1" : "=v"(cvl[c][u]) : "v"(srch + 256 + u * 8) : "memory");
                    }
                }
            }
            asm volatile("s_waitcnt vmcnt(0)" ::: "memory");
            __builtin_amdgcn_sched_barrier(0);
#pragma unroll
            for (int c = 0; c < 2; c++) {
#pragma unroll
                for (int u = 0; u < 2; u++) {
                    int jb = (seg * 16 + u * 8) * 2;
                    *(half8*)((char*)(&Ah[c][0] + b16 * 384) + 256 + (jb ^ bswz)) = cvh[c][u];
                    *(half8*)((char*)(&Al[c][0] + b16 * 256) + (jb ^ bswz)) = cvl[c][u];
                }
                *(half8*)((char*)(&Ah[c][0] + b16 * 384) + ((seg * 16) ^ bswz)) = xp[c];
            }
            asm volatile("s_waitcnt lgkmcnt(0)" ::: "memory");
            __builtin_amdgcn_s_barrier();                   // B3: next-step operands staged
        }
    }
}

// ---------------- attention context ----------------
template<typename HT>
__global__ __launch_bounds__(256) void attn_ctx_kernel(const HT* __restrict__ hs_s, const HT* __restrict__ hs_m,
                                                       float* __restrict__ ctx_s, float* __restrict__ ctx_m)
{
    const int b = blockIdx.x;
    const int L = blockIdx.y;
    const HT* hsb = (L ? hs_m : hs_s) + (size_t)b * S * H;
    float* ctx = (L ? ctx_m : ctx_s) + b * H;
    const int tid = threadIdx.x;
    const int wv = tid >> 6, l = tid & 63;

    __shared__ float hlast[H];
    __shared__ float score[S];
    __shared__ float dist[S];
    __shared__ float red[4];

    hlast[tid] = cvtf(hsb[(size_t)(S - 1) * H + tid]);
    __syncthreads();

    const int segl = l & 15;
    for (int it = 0; it < 16; ++it) {
        int row = it * 16 + wv * 4 + (l >> 4);
        float s = 0.f;
        if constexpr (sizeof(HT) == 2) {
            const half8* p = (const half8*)(hsb + (size_t)row * H + segl * 16);
#pragma unroll
            for (int u = 0; u < 2; u++) {
                half8 v = p[u];
#pragma unroll
                for (int j = 0; j < 8; j++) s = fmaf((float)v[j], hlast[segl * 16 + u * 8 + j], s);
            }
        } else {
            const float4* p = (const float4*)(hsb + (size_t)row * H + segl * 16);
#pragma unroll
            for (int u = 0; u < 4; u++) {
                float4 v = p[u];
                s = fmaf(v.x, hlast[segl * 16 + u * 4 + 0], s);
                s = fmaf(v.y, hlast[segl * 16 + u * 4 + 1], s);
                s = fmaf(v.z, hlast[segl * 16 + u * 4 + 2], s);
                s = fmaf(v.w, hlast[segl * 16 + u * 4 + 3], s);
            }
        }
        s += __shfl_xor(s, 1); s += __shfl_xor(s, 2); s += __shfl_xor(s, 4); s += __shfl_xor(s, 8);
        if (segl == 0) score[row] = s;
    }
    __syncthreads();

    float sct = score[tid];
    float v = sct;
    for (int o = 32; o > 0; o >>= 1) v += __shfl_down(v, o);
    if ((tid & 63) == 0) red[tid >> 6] = v;
    __syncthreads();
    float denom = red[0] + red[1] + red[2] + red[3];
    dist[tid] = sct / denom;
    __syncthreads();

    float acc = 0.f;
    for (int t = 0; t < S; ++t) acc = fmaf(dist[t], cvtf(hsb[(size_t)t * H + tid]), acc);
    ctx[tid] = acc;
}

// ---------------- tail ----------------
__global__ __launch_bounds__(256) void tail_kernel(
    const float* __restrict__ ctx_s, const float* __restrict__ ctx_m,
    const float* __restrict__ norm_w, const float* __restrict__ norm_b,
    const float* __restrict__ macro_w,
    const float* __restrict__ in_wT, const float* __restrict__ in_b,
    const float* __restrict__ outp_wT, const float* __restrict__ outp_b,
    const float* __restrict__ w1T, const float* __restrict__ b1,
    const float* __restrict__ w2T, const float* __restrict__ b2,
    const float* __restrict__ fw, const float* __restrict__ fb,
    float* __restrict__ out)
{
    const int b = blockIdx.x;
    const int tid = threadIdx.x;

    __shared__ float ml[NS][H];
    __shared__ float buf[NS][H];
    __shared__ float qh[NS][DH], kh[NS][DH], vh[NS][DH], sc[NS][NS];
    __shared__ float red[4];

    float cs = ctx_s[b * H + tid];
    float v = cs;
    for (int o = 32; o > 0; o >>= 1) v += __shfl_down(v, o);
    if ((tid & 63) == 0) red[tid >> 6] = v;
    __syncthreads();
    float mean = (red[0] + red[1] + red[2] + red[3]) * (1.f / H);
    float dv = cs - mean;
    __syncthreads();
    v = dv * dv;
    for (int o = 32; o > 0; o >>= 1) v += __shfl_down(v, o);
    if ((tid & 63) == 0) red[tid >> 6] = v;
    __syncthreads();
    float stdv = sqrtf((red[0] + red[1] + red[2] + red[3]) * (1.f / (H - 1))) + 1e-8f;
    float z = dv / stdv;
    float cm = ctx_m[b * H + tid];
    float mwv = macro_w[0];
    for (int n = 0; n < NS; ++n)
        ml[n][tid] = norm_w[n * H + tid] * z + norm_b[n * H + tid] + mwv * cm;
    __syncthreads();

    const int dloc = tid & 31;
    const int iset = tid >> 5;
    const float scale = 0.17677669529663687f;
    for (int h = 0; h < NH; ++h) {
        {
            int rq = h * DH + dloc;
            float aq[4], ak[4], av[4];
#pragma unroll
            for (int rr = 0; rr < 4; rr++) { aq[rr] = in_b[rq]; ak[rr] = in_b[H + rq]; av[rr] = in_b[2 * H + rq]; }
            for (int k = 0; k < H; ++k) {
                float wq = in_wT[k * 768 + rq];
                float wk = in_wT[k * 768 + 256 + rq];
                float wv = in_wT[k * 768 + 512 + rq];
#pragma unroll
                for (int rr = 0; rr < 4; rr++) {
                    float m = ml[iset + 8 * rr][k];
                    aq[rr] = fmaf(m, wq, aq[rr]); ak[rr] = fmaf(m, wk, ak[rr]); av[rr] = fmaf(m, wv, av[rr]);
                }
            }
#pragma unroll
            for (int rr = 0; rr < 4; rr++) { qh[iset + 8 * rr][dloc] = aq[rr]; kh[iset + 8 * rr][dloc] = ak[rr]; vh[iset + 8 * rr][dloc] = av[rr]; }
        }
        __syncthreads();
        {
            int i = tid >> 3;
            int j0 = (tid & 7) * 4;
            float a[4] = { 0.f, 0.f, 0.f, 0.f };
            for (int d = 0; d < DH; ++d) {
                float q = qh[i][d];
#pragma unroll
                for (int jj = 0; jj < 4; jj++) a[jj] = fmaf(q, kh[j0 + jj][d], a[jj]);
            }
#pragma unroll
            for (int jj = 0; jj < 4; jj++) sc[i][j0 + jj] = a[jj] * scale;
        }
        __syncthreads();
        if (tid < NS) {
            float mx = -1e30f;
            for (int j = 0; j < NS; j++) mx = fmaxf(mx, sc[tid][j]);
            float sm = 0.f, e[NS];
            for (int j = 0; j < NS; j++) { e[j] = __expf(sc[tid][j] - mx); sm += e[j]; }
            float inv = 1.f / sm;
            for (int j = 0; j < NS; j++) sc[tid][j] = e[j] * inv;
        }
        __syncthreads();
        {
            int i = tid >> 3;
            int d0 = (tid & 7) * 4;
            float a[4] = { 0.f, 0.f, 0.f, 0.f };
            for (int j = 0; j < NS; ++j) {
                float sv = sc[i][j];
#pragma unroll
                for (int dd = 0; dd < 4; dd++) a[dd] = fmaf(sv, vh[j][d0 + dd], a[dd]);
            }
#pragma unroll
            for (int dd = 0; dd < 4; dd++) buf[i][h * DH + d0 + dd] = a[dd];
        }
        __syncthreads();
    }

    {
        float acc32[NS];
        float ob = outp_b[tid];
#pragma unroll
        for (int t = 0; t < NS; t++) acc32[t] = ob;
        for (int k = 0; k < H; ++k) {
            float w = outp_wT[k * H + tid];
#pragma unroll
            for (int t = 0; t < NS; t++) acc32[t] = fmaf(buf[t][k], w, acc32[t]);
        }
#pragma unroll
        for (int t = 0; t < NS; t++) ml[t][tid] += acc32[t];
    }
    __syncthreads();

    float acc_o[NS];
    {
        float b2v = b2[tid];
#pragma unroll
        for (int t = 0; t < NS; t++) acc_o[t] = b2v;
    }
    for (int jc = 0; jc < 4; ++jc) {
        float hid[NS];
        {
            float b1v = b1[jc * H + tid];
#pragma unroll
            for (int t = 0; t < NS; t++) hid[t] = b1v;
            for (int k = 0; k < H; ++k) {
                float w = w1T[k * G4 + jc * H + tid];
#pragma unroll
                for (int t = 0; t < NS; t++) hid[t] = fmaf(ml[t][k], w, hid[t]);
            }
        }
        __syncthreads();
#pragma unroll
        for (int t = 0; t < NS; t++) buf[t][tid] = fmaxf(hid[t], 0.f);
        __syncthreads();
        for (int k = 0; k < H; ++k) {
            float w = w2T[(jc * H + k) * H + tid];
#pragma unroll
            for (int t = 0; t < NS; t++) acc_o[t] = fmaf(buf[t][k], w, acc_o[t]);
        }
        __syncthreads();
    }

    float p = 0.f;
#pragma unroll
    for (int t = 0; t < NS; t++) p += tanhf(ml[t][tid] + acc_o[t]);
    p *= (1.f / NS);
    v = p * fw[tid];
    for (int o = 32; o > 0; o >>= 1) v += __shfl_down(v, o);
    if ((tid & 63) == 0) red[tid >> 6] = v;
    __syncthreads();
    if (tid == 0) out[b] = red[0] + red[1] + red[2] + red[3] + fb[0];
}

// ---------------- host ----------------
extern "C" void kernel_launch(void* const* d_in, const int* in_sizes, int n_in,
                              void* d_out, int out_size, void* d_ws, size_t ws_size,
                              hipStream_t stream) {
    const float* x      = (const float*)d_in[0];
    const float* stw    = (const float*)d_in[1];
    const float* stb    = (const float*)d_in[2];
    const float* mtw    = (const float*)d_in[3];
    const float* mtb    = (const float*)d_in[4];
    const float* s_wih  = (const float*)d_in[5];
    const float* s_whh  = (const float*)d_in[6];
    const float* s_bih  = (const float*)d_in[7];
    const float* s_bhh  = (const float*)d_in[8];
    const float* m_wih  = (const float*)d_in[9];
    const float* m_whh  = (const float*)d_in[10];
    const float* m_bih  = (const float*)d_in[11];
    const float* m_bhh  = (const float*)d_in[12];
    const float* norm_w = (const float*)d_in[13];
    const float* norm_b = (const float*)d_in[14];
    const float* macro_w= (const float*)d_in[15];
    const float* in_w   = (const float*)d_in[16];
    const float* in_b   = (const float*)d_in[17];
    const float* outp_w = (const float*)d_in[18];
    const float* outp_b = (const float*)d_in[19];
    const float* w1     = (const float*)d_in[20];
    const float* b1     = (const float*)d_in[21];
    const float* w2     = (const float*)d_in[22];
    const float* b2     = (const float*)d_in[23];
    const float* fw     = (const float*)d_in[24];
    const float* fb     = (const float*)d_in[25];
    float* out = (float*)d_out;

    // workspace layout (256B-aligned blocks)
    size_t off = 0;
    auto alloc = [&](size_t bytes) { char* q = (char*)d_ws + off; off += (bytes + 255) & ~(size_t)255; return q; };
    _Float16* W16h  = (_Float16*)alloc((size_t)2 * 8 * 128 * 384 * 2);
    _Float16* W16l  = (_Float16*)alloc((size_t)2 * 8 * 128 * 256 * 2);
    float*    biasP = (float*)alloc((size_t)2 * 8 * 128 * 4);
    _Float16* trW16 = (_Float16*)alloc((size_t)256 * 128 * 2);
    _Float16* hG    = (_Float16*)alloc((size_t)32 * 2 * 2 * 16 * 512 * 2);            // 2 MB
    unsigned int* flags = (unsigned int*)alloc((size_t)32 * 256 * 2 * 8 * 4 * 4);     // 8 MB
    float*    ctx_s = (float*)alloc((size_t)B * H * 4);
    float*    ctx_m = (float*)alloc((size_t)B * H * 4);
    float*    in_wT = (float*)alloc((size_t)H * 768 * 4);
    float*    outp_wT = (float*)alloc((size_t)H * H * 4);
    float*    w1T   = (float*)alloc((size_t)H * G4 * 4);
    float*    w2T   = (float*)alloc((size_t)G4 * H * 4);
    _Float16* xtr16 = (_Float16*)alloc((size_t)2 * B * S * 128 * 2);                  // 64 MiB
    size_t off_before_hs = off;
    const size_t hs_elems = (size_t)2 * B * S * H;
    const size_t need_full = off_before_hs + hs_elems * sizeof(float) + (1u << 20);
    const bool f32hs = ws_size >= need_full;

    prep_kernel<<<128, 256, 0, stream>>>(s_wih, s_whh, s_bih, s_bhh,
                                         m_wih, m_whh, m_bih, m_bhh,
                                         stw, mtw, in_w, outp_w, w1, w2,
                                         W16h, W16l, biasP, trW16,
                                         in_wT, outp_wT, w1T, w2T);
    xtr_kernel<<<B, 256, 0, stream>>>(x, trW16, stb, mtb, xtr16);
    (void)hipMemsetAsync(flags, 0, (size_t)32 * 256 * 2 * 8 * 4 * 4, stream);

    if (f32hs) {
        float* hs = (float*)alloc(hs_elems * sizeof(float));
        lstm_mfma<float><<<256, 256, 0, stream>>>(W16h, W16l, biasP, xtr16, hs, hG, flags);
        attn_ctx_kernel<float><<<dim3(B, 2), 256, 0, stream>>>(hs, hs + hs_elems / 2, ctx_s, ctx_m);
    } else {
        _Float16* hs = (_Float16*)alloc(hs_elems * sizeof(_Float16));
        lstm_mfma<_Float16><<<256, 256, 0, stream>>>(W16h, W16l, biasP, xtr16, hs, hG, flags);
        attn_ctx_kernel<_Float16><<<dim3(B, 2), 256, 0, stream>>>(hs, hs + hs_elems / 2, ctx_s, ctx_m);
    }

    tail_kernel<<<B, 256, 0, stream>>>(ctx_s, ctx_m,
                                       norm_w, norm_b, macro_w,
                                       in_wT, in_b, outp_wT, outp_b,
                                       w1T, b1, w2T, b2, fw, fb, out);
}

// Round 13
// 2141.071 us; speedup vs baseline: 1.1493x; 1.0495x over previous
//
#include <hip/hip_runtime.h>
#include <hip/hip_bf16.h>
#include <math.h>

#define B 512
#define S 256
#define D 128
#define H 256
#define G4 1024
#define NS 32
#define NH 8
#define DH 32

typedef _Float16 half8 __attribute__((ext_vector_type(8)));
typedef _Float16 half4v __attribute__((ext_vector_type(4)));
typedef _Float16 half2v __attribute__((ext_vector_type(2)));
typedef float f32x4 __attribute__((ext_vector_type(4)));

__device__ __forceinline__ float sigm(float v) { return 1.f / (1.f + __expf(-v)); }
__device__ __forceinline__ float tanh_fast(float x) { float e = __expf(2.f * x); return 1.f - 2.f / (e + 1.f); }
__device__ __forceinline__ float cvtf(float v) { return v; }
__device__ __forceinline__ float cvtf(_Float16 v) { return (float)v; }

// ---------------- prep ----------------
__global__ void prep_kernel(const float* __restrict__ s_wih, const float* __restrict__ s_whh,
                            const float* __restrict__ s_bih, const float* __restrict__ s_bhh,
                            const float* __restrict__ m_wih, const float* __restrict__ m_whh,
                            const float* __restrict__ m_bih, const float* __restrict__ m_bhh,
                            const float* __restrict__ stw, const float* __restrict__ mtw,
                            const float* __restrict__ in_w, const float* __restrict__ outp_w,
                            const float* __restrict__ w1, const float* __restrict__ w2,
                            _Float16* __restrict__ W16h, _Float16* __restrict__ W16l,
                            float* __restrict__ biasP, _Float16* __restrict__ trW16,
                            float* __restrict__ in_wT, float* __restrict__ outp_wT,
                            float* __restrict__ w1T, float* __restrict__ w2T)
{
    int tid = blockIdx.x * blockDim.x + threadIdx.x;
    int stride = gridDim.x * blockDim.x;
    for (int i = tid; i < 2 * 8 * 128 * 384; i += stride) {
        int k = i % 384; int n = (i / 384) % 128; int c = (i / (384 * 128)) % 8; int L = i / (384 * 128 * 8);
        int row = (n >> 5) * 256 + c * 32 + (n & 31);
        const float* wih = L ? m_wih : s_wih;
        const float* whh = L ? m_whh : s_whh;
        float v = (k < 128) ? wih[row * 128 + k] : whh[row * 256 + (k - 128)];
        W16h[i] = (_Float16)v;
    }
    for (int i = tid; i < 2 * 8 * 128 * 256; i += stride) {
        int k = i % 256; int n = (i / 256) % 128; int c = (i / (256 * 128)) % 8; int L = i / (256 * 128 * 8);
        int row = (n >> 5) * 256 + c * 32 + (n & 31);
        const float* whh = L ? m_whh : s_whh;
        float v = whh[row * 256 + k];
        _Float16 hi = (_Float16)v;
        W16l[i] = (_Float16)(v - (float)hi);
    }
    for (int i = tid; i < 2 * 8 * 128; i += stride) {
        int n = i % 128; int c = (i / 128) % 8; int L = i / (128 * 8);
        int row = (n >> 5) * 256 + c * 32 + (n & 31);
        biasP[i] = L ? (m_bih[row] + m_bhh[row]) : (s_bih[row] + s_bhh[row]);
    }
    for (int i = tid; i < 256 * 128; i += stride) {
        int k = i % 128, n = i / 128;
        trW16[i] = (_Float16)(n < 128 ? stw[n * 128 + k] : mtw[(n - 128) * 128 + k]);
    }
    for (int i = tid; i < H * 768; i += stride)  { int k = i / 768, n = i % 768;  in_wT[i]  = in_w[n * H + k]; }
    for (int i = tid; i < H * H; i += stride)    { int k = i / H,   n = i % H;    outp_wT[i]= outp_w[n * H + k]; }
    for (int i = tid; i < H * G4; i += stride)   { int k = i / G4,  n = i % G4;   w1T[i]    = w1[n * H + k]; }
    for (int i = tid; i < G4 * H; i += stride)   { int k2 = i / H,  n = i % H;    w2T[i]    = w2[n * G4 + k2]; }
}

// ---------------- xtr ----------------
__global__ __launch_bounds__(256, 1) void xtr_kernel(const float* __restrict__ x,
        const _Float16* __restrict__ trW16,
        const float* __restrict__ stb, const float* __restrict__ mtb,
        _Float16* __restrict__ xtr16)
{
    const int b = blockIdx.x;
    const int tid = threadIdx.x;
    const int w = tid >> 6, l = tid & 63, l15 = l & 15, l4 = l >> 4;

    __shared__ _Float16 xa[128 * 128];

    half8 bw[4][4];
#pragma unroll
    for (int kk = 0; kk < 4; kk++)
#pragma unroll
        for (int ni = 0; ni < 4; ni++)
            bw[kk][ni] = *(const half8*)(trW16 + (w * 64 + ni * 16 + l15) * 128 + kk * 32 + l4 * 8);
    float tb[4];
#pragma unroll
    for (int ni = 0; ni < 4; ni++) { int d = w * 64 + ni * 16 + l15; tb[ni] = d < 128 ? stb[d] : mtb[d - 128]; }

    for (int h2 = 0; h2 < 2; ++h2) {
        {
            int trow = tid >> 1, seg = tid & 1;
            const float* src = x + ((size_t)b * S + h2 * 128 + trow) * 128 + seg * 64;
            int swz = (trow & 7) << 4;
#pragma unroll
            for (int q8 = 0; q8 < 8; q8++) {
                float4 f0 = *(const float4*)(src + q8 * 8);
                float4 f1 = *(const float4*)(src + q8 * 8 + 4);
                half8 hv = { (_Float16)f0.x, (_Float16)f0.y, (_Float16)f0.z, (_Float16)f0.w,
                             (_Float16)f1.x, (_Float16)f1.y, (_Float16)f1.z, (_Float16)f1.w };
                int byte = ((seg * 64 + q8 * 8) * 2) ^ swz;
                *(half8*)((char*)(xa + trow * 128) + byte) = hv;
            }
        }
        __syncthreads();
        for (int mt = 0; mt < 8; ++mt) {
            int row = mt * 16 + l15;
            int swz = (row & 7) << 4;
            half8 af[4];
#pragma unroll
            for (int kk = 0; kk < 4; kk++) {
                int byte = ((kk * 32 + l4 * 8) * 2) ^ swz;
                af[kk] = *(const half8*)((const char*)(xa + row * 128) + byte);
            }
            f32x4 acc[4];
#pragma unroll
            for (int ni = 0; ni < 4; ni++) acc[ni] = (f32x4){ tb[ni], tb[ni], tb[ni], tb[ni] };
#pragma unroll
            for (int kk = 0; kk < 4; kk++)
#pragma unroll
                for (int ni = 0; ni < 4; ni++)
                    acc[ni] = __builtin_amdgcn_mfma_f32_16x16x32_f16(af[kk], bw[kk][ni], acc[ni], 0, 0, 0);
#pragma unroll
            for (int ni = 0; ni < 4; ni++) {
                int d = w * 64 + ni * 16 + l15;
                int Ls = d >> 7, dl = d & 127;
#pragma unroll
                for (int r = 0; r < 4; r++) {
                    int t = h2 * 128 + mt * 16 + l4 * 4 + r;
                    xtr16[(((size_t)Ls * B + b) * S + t) * 128 + dl] = (_Float16)tanh_fast(acc[ni][r]);
                }
            }
        }
        __syncthreads();
    }
}

// ---------------- persistent MFMA LSTM ----------------
// grid 256: bid = sC*32 + r ; r = L*16 + btp ; chain c batches = btp*32 + c*16 .. +15
// h-exchange: hi-only payload (W_lo correction kept locally; h_lo term dropped).
// Flags are monotonic step-tags at fixed, line-padded addresses (64B per writer-wave slot):
// value t+1 published after counted-vmcnt drain of that chain's exchange store. Readers
// poll >= t+1 (writer leads any reader by at most 1 step; parity slots disjoint).
#define LSTM_GATES(c)                                                                   \
    {                                                                                   \
        f32x4 a0 = (f32x4){ bn[0], bn[0], bn[0], bn[0] };                               \
        f32x4 a1 = (f32x4){ bn[1], bn[1], bn[1], bn[1] };                               \
        const char* ahBase = (const char*)(&Ah[c][0] + l15 * 384);                      \
        _Pragma("unroll")                                                               \
        for (int kk = 0; kk < 4; kk++) {                                                \
            half8 ah = *(const half8*)(ahBase + (((kk * 32 + l4 * 8) * 2) ^ aswz));     \
            a0 = __builtin_amdgcn_mfma_f32_16x16x32_f16(ah, bwh[kk][0], a0, 0, 0, 0);   \
            a1 = __builtin_amdgcn_mfma_f32_16x16x32_f16(ah, bwh[kk][1], a1, 0, 0, 0);   \
        }                                                                               \
        _Pragma("unroll")                                                               \
        for (int kk = 4; kk < 12; kk++) {                                               \
            int jb = ((kk - 4) * 32 + l4 * 8) * 2;                                      \
            half8 ah = *(const half8*)(ahBase + 256 + (jb ^ aswz));                     \
            a0 = __builtin_amdgcn_mfma_f32_16x16x32_f16(ah, bwh[kk][0], a0, 0, 0, 0);   \
            a0 = __builtin_amdgcn_mfma_f32_16x16x32_f16(ah, bwlo[kk - 4][0], a0, 0, 0, 0); \
            a1 = __builtin_amdgcn_mfma_f32_16x16x32_f16(ah, bwh[kk][1], a1, 0, 0, 0);   \
            a1 = __builtin_amdgcn_mfma_f32_16x16x32_f16(ah, bwlo[kk - 4][1], a1, 0, 0, 0); \
        }                                                                               \
        _Pragma("unroll")                                                               \
        for (int q = 0; q < 4; q++) {                                                   \
            gl[c][l4 * 4 + q][w * 32 + l15] = a0[q];                                    \
            gl[c][l4 * 4 + q][w * 32 + 16 + l15] = a1[q];                               \
        }                                                                               \
    }

// pw: exchange store (1 inst, hi only) then hs store (1 inst) -> FIFO counted later
#define LSTM_PW(c)                                                                      \
    {                                                                                   \
        int j2 = seg * 2;                                                               \
        float2 iv = *(const float2*)&gl[c][b16][0 + j2];                                \
        float2 fv = *(const float2*)&gl[c][b16][32 + j2];                               \
        float2 gv = *(const float2*)&gl[c][b16][64 + j2];                               \
        float2 ov = *(const float2*)&gl[c][b16][96 + j2];                               \
        float iq[2] = { iv.x, iv.y }, fq[2] = { fv.x, fv.y };                           \
        float gq[2] = { gv.x, gv.y }, oq[2] = { ov.x, ov.y };                           \
        float hv[2]; _Float16 hh[2];                                                    \
        _Pragma("unroll")                                                               \
        for (int q = 0; q < 2; q++) {                                                   \
            float cc = sigm(fq[q]) * cst[c][q] + sigm(iq[q]) * tanh_fast(gq[q]);        \
            cst[c][q] = cc;                                                             \
            hv[q] = sigm(oq[q]) * tanh_fast(cc);                                        \
            hh[q] = (_Float16)hv[q];                                                    \
        }                                                                               \
        if (more) {                                                                     \
            _Float16* dst = hG + ((size_t)(r * 2 + (c)) * 2 + par) * 16 * 256 + b16 * 256 + sC * 32 + j2; \
            half2v phi = { hh[0], hh[1] };                                              \
            asm volatile("global_store_dword %0, %1, off sc0 sc1" :: "v"(dst), "v"(phi) : "memory"); \
        }                                                                               \
        size_t hidx = (((size_t)L * B + b0 + (c) * 16 + b16) * S + t) * H + sC * 32 + j2; \
        if constexpr (sizeof(HT) == 4) {                                                \
            float2 hv2 = make_float2(hv[0], hv[1]);                                     \
            asm volatile("global_store_dwordx2 %0, %1, off" :: "v"((float*)hs + hidx), "v"(hv2) : "memory"); \
        } else {                                                                        \
            half2v ph = { hh[0], hh[1] };                                               \
            asm volatile("global_store_dword %0, %1, off" :: "v"((_Float16*)hs + hidx), "v"(ph) : "memory"); \
        }                                                                               \
    }

template<typename HT>
__global__ __launch_bounds__(256, 1) void lstm_mfma(
    const _Float16* __restrict__ W16h, const _Float16* __restrict__ W16l,
    const float* __restrict__ biasP,
    const _Float16* __restrict__ xtr16,
    HT* __restrict__ hs, _Float16* __restrict__ hG, unsigned int* __restrict__ flags)
{
    const int bid = blockIdx.x;
    const int sC = bid >> 5;
    const int r  = bid & 31;
    const int L  = r >> 4;
    const int btp = r & 15;
    const int b0 = btp * 32;
    const int tid = threadIdx.x;
    const int w = tid >> 6, l = tid & 63, l15 = l & 15, l4 = l >> 4;

    __shared__ _Float16 Ah[2][16 * 384];
    __shared__ float gl[2][16][132];

    for (int i = tid; i < 2 * 16 * 384 * 2 / 16; i += 256) ((int4*)&Ah[0][0])[i] = make_int4(0, 0, 0, 0);

    const size_t wbh = ((size_t)(L * 8 + sC) * 128) * 384;
    const size_t wbl = ((size_t)(L * 8 + sC) * 128) * 256;
    half8 bwh[12][2], bwlo[8][2];
#pragma unroll
    for (int kk = 0; kk < 12; kk++)
#pragma unroll
        for (int ni = 0; ni < 2; ni++)
            bwh[kk][ni] = *(const half8*)(W16h + wbh + (size_t)(w * 32 + ni * 16 + l15) * 384 + kk * 32 + l4 * 8);
#pragma unroll
    for (int kk = 0; kk < 8; kk++)
#pragma unroll
        for (int ni = 0; ni < 2; ni++)
            bwlo[kk][ni] = *(const half8*)(W16l + wbl + (size_t)(w * 32 + ni * 16 + l15) * 256 + kk * 32 + l4 * 8);
    float bn[2];
#pragma unroll
    for (int ni = 0; ni < 2; ni++) bn[ni] = biasP[(L * 8 + sC) * 128 + w * 32 + ni * 16 + l15];

    const int b16 = tid >> 4;
    const int seg = tid & 15;
    const int bswz = (b16 & 7) << 4;
    const int aswz = (l15 & 7) << 4;

#pragma unroll
    for (int c = 0; c < 2; c++) {
        const _Float16* src = xtr16 + (((size_t)L * B + b0 + c * 16 + b16) * S + 0) * 128 + seg * 8;
        half8 v0 = *(const half8*)src;
        *(half8*)((char*)(&Ah[c][0] + b16 * 384) + ((seg * 16) ^ bswz)) = v0;
    }
    float cst[2][2] = { { 0.f, 0.f }, { 0.f, 0.f } };
    half8 xp[2];
    half8 cvh[2][2];
    // line-padded monotonic tag slots: 64B per (chain, writer-WG, wave)
    unsigned int* wf0 = flags + (((size_t)(r * 2 + 0) * 8 + sC) * 4 + w) * 16;
    unsigned int* wf1 = flags + (((size_t)(r * 2 + 1) * 8 + sC) * 4 + w) * 16;
    const unsigned int* pf0 = flags + (((size_t)(r * 2 + 0) * 8 + (seg >> 1)) * 4 + w) * 16;
    const unsigned int* pf1 = flags + (((size_t)(r * 2 + 1) * 8 + (seg >> 1)) * 4 + w) * 16;
    __syncthreads();

    for (int t = 0; t < S; ++t) {
        const int par = t & 1;
        const bool more = (t < S - 1);

        LSTM_GATES(0)
        asm volatile("s_waitcnt lgkmcnt(0)" ::: "memory");
        __builtin_amdgcn_s_barrier();                       // B1: gl[0] visible

        LSTM_PW(0)                                          // exch0 + hs0 issued
        LSTM_GATES(1)                                       // exch0 drains under MFMA
        asm volatile("s_waitcnt lgkmcnt(0)" ::: "memory");
        __builtin_amdgcn_s_barrier();                       // B2: gl[1] visible

        LSTM_PW(1)                                          // exch1 + hs1 issued

        if (more) {
            unsigned int tagv = (unsigned int)(t + 1);
            asm volatile("s_waitcnt vmcnt(3)" ::: "memory");   // exch0 at L3
            if (l == 0)
                asm volatile("global_store_dword %0, %1, off sc0 sc1" :: "v"(wf0), "v"(tagv) : "memory");
            asm volatile("s_waitcnt vmcnt(1)" ::: "memory");   // exch1 at L3 (hs0 too)
            if (l == 0)
                asm volatile("global_store_dword %0, %1, off sc0 sc1" :: "v"(wf1), "v"(tagv) : "memory");
            // xtr prefetch (drains under polls)
#pragma unroll
            for (int c = 0; c < 2; c++) {
                const _Float16* src = xtr16 + (((size_t)L * B + b0 + c * 16 + b16) * S + (t + 1)) * 128 + seg * 8;
                asm volatile("global_load_dwordx4 %0, %1, off" : "=v"(xp[c]) : "v"(src) : "memory");
            }
            // combined spin on both chains' tags (monotonic: >= t+1)
            {
                unsigned int v0, v1;
                while (true) {
                    asm volatile("global_load_dword %0, %2, off sc0 sc1\n\t"
                                 "global_load_dword %1, %3, off sc0 sc1\n\t"
                                 "s_waitcnt vmcnt(0)"
                                 : "=v"(v0), "=v"(v1) : "v"(pf0), "v"(pf1) : "memory");
                    if (v0 > (unsigned int)t && v1 > (unsigned int)t) break;
                    __builtin_amdgcn_s_sleep(1);
                }
            }
            // both chains' data in one burst
            {
                const _Float16* s0 = hG + ((size_t)(r * 2 + 0) * 2 + par) * 16 * 256 + b16 * 256 + seg * 16;
                const _Float16* s1 = hG + ((size_t)(r * 2 + 1) * 2 + par) * 16 * 256 + b16 * 256 + seg * 16;
                asm volatile("global_load_dwordx4 %0, %1, off sc0 sc1" : "=v"(cvh[0][0]) : "v"(s0) : "memory");
                asm volatile("global_load_dwordx4 %0, %1, off sc0 sc1" : "=v"(cvh[0][1]) : "v"(s0 + 8) : "memory");
                asm volatile("global_load_dwordx4 %0, %1, off sc0 sc1" : "=v"(cvh[1][0]) : "v"(s1) : "memory");
                asm volatile("global_load_dwordx4 %0, %1, off sc0 sc1" : "=v"(cvh[1][1]) : "v"(s1 + 8) : "memory");
                asm volatile("s_waitcnt vmcnt(0)" ::: "memory");
                __builtin_amdgcn_sched_barrier(0);
            }
#pragma unroll
            for (int c = 0; c < 2; c++) {
#pragma unroll
                for (int u = 0; u < 2; u++) {
                    int jb = (seg * 16 + u * 8) * 2;
                    *(half8*)((char*)(&Ah[c][0] + b16 * 384) + 256 + (jb ^ bswz)) = cvh[c][u];
                }
                *(half8*)((char*)(&Ah[c][0] + b16 * 384) + ((seg * 16) ^ bswz)) = xp[c];
            }
            asm volatile("s_waitcnt lgkmcnt(0)" ::: "memory");
            __builtin_amdgcn_s_barrier();                   // B3: next-step operands staged
        }
    }
}

// ---------------- attention context ----------------
template<typename HT>
__global__ __launch_bounds__(256) void attn_ctx_kernel(const HT* __restrict__ hs_s, const HT* __restrict__ hs_m,
                                                       float* __restrict__ ctx_s, float* __restrict__ ctx_m)
{
    const int b = blockIdx.x;
    const int L = blockIdx.y;
    const HT* hsb = (L ? hs_m : hs_s) + (size_t)b * S * H;
    float* ctx = (L ? ctx_m : ctx_s) + b * H;
    const int tid = threadIdx.x;
    const int wv = tid >> 6, l = tid & 63;

    __shared__ float hlast[H];
    __shared__ float score[S];
    __shared__ float dist[S];
    __shared__ float red[4];

    hlast[tid] = cvtf(hsb[(size_t)(S - 1) * H + tid]);
    __syncthreads();

    const int segl = l & 15;
    for (int it = 0; it < 16; ++it) {
        int row = it * 16 + wv * 4 + (l >> 4);
        float s = 0.f;
        if constexpr (sizeof(HT) == 2) {
            const half8* p = (const half8*)(hsb + (size_t)row * H + segl * 16);
#pragma unroll
            for (int u = 0; u < 2; u++) {
                half8 v = p[u];
#pragma unroll
                for (int j = 0; j < 8; j++) s = fmaf((float)v[j], hlast[segl * 16 + u * 8 + j], s);
            }
        } else {
            const float4* p = (const float4*)(hsb + (size_t)row * H + segl * 16);
#pragma unroll
            for (int u = 0; u < 4; u++) {
                float4 v = p[u];
                s = fmaf(v.x, hlast[segl * 16 + u * 4 + 0], s);
                s = fmaf(v.y, hlast[segl * 16 + u * 4 + 1], s);
                s = fmaf(v.z, hlast[segl * 16 + u * 4 + 2], s);
                s = fmaf(v.w, hlast[segl * 16 + u * 4 + 3], s);
            }
        }
        s += __shfl_xor(s, 1); s += __shfl_xor(s, 2); s += __shfl_xor(s, 4); s += __shfl_xor(s, 8);
        if (segl == 0) score[row] = s;
    }
    __syncthreads();

    float sct = score[tid];
    float v = sct;
    for (int o = 32; o > 0; o >>= 1) v += __shfl_down(v, o);
    if ((tid & 63) == 0) red[tid >> 6] = v;
    __syncthreads();
    float denom = red[0] + red[1] + red[2] + red[3];
    dist[tid] = sct / denom;
    __syncthreads();

    float acc = 0.f;
    for (int t = 0; t < S; ++t) acc = fmaf(dist[t], cvtf(hsb[(size_t)t * H + tid]), acc);
    ctx[tid] = acc;
}

// ---------------- tail ----------------
__global__ __launch_bounds__(256) void tail_kernel(
    const float* __restrict__ ctx_s, const float* __restrict__ ctx_m,
    const float* __restrict__ norm_w, const float* __restrict__ norm_b,
    const float* __restrict__ macro_w,
    const float* __restrict__ in_wT, const float* __restrict__ in_b,
    const float* __restrict__ outp_wT, const float* __restrict__ outp_b,
    const float* __restrict__ w1T, const float* __restrict__ b1,
    const float* __restrict__ w2T, const float* __restrict__ b2,
    const float* __restrict__ fw, const float* __restrict__ fb,
    float* __restrict__ out)
{
    const int b = blockIdx.x;
    const int tid = threadIdx.x;

    __shared__ float ml[NS][H];
    __shared__ float buf[NS][H];
    __shared__ float qh[NS][DH], kh[NS][DH], vh[NS][DH], sc[NS][NS];
    __shared__ float red[4];

    float cs = ctx_s[b * H + tid];
    float v = cs;
    for (int o = 32; o > 0; o >>= 1) v += __shfl_down(v, o);
    if ((tid & 63) == 0) red[tid >> 6] = v;
    __syncthreads();
    float mean = (red[0] + red[1] + red[2] + red[3]) * (1.f / H);
    float dv = cs - mean;
    __syncthreads();
    v = dv * dv;
    for (int o = 32; o > 0; o >>= 1) v += __shfl_down(v, o);
    if ((tid & 63) == 0) red[tid >> 6] = v;
    __syncthreads();
    float stdv = sqrtf((red[0] + red[1] + red[2] + red[3]) * (1.f / (H - 1))) + 1e-8f;
    float z = dv / stdv;
    float cm = ctx_m[b * H + tid];
    float mwv = macro_w[0];
    for (int n = 0; n < NS; ++n)
        ml[n][tid] = norm_w[n * H + tid] * z + norm_b[n * H + tid] + mwv * cm;
    __syncthreads();

    const int dloc = tid & 31;
    const int iset = tid >> 5;
    const float scale = 0.17677669529663687f;
    for (int h = 0; h < NH; ++h) {
        {
            int rq = h * DH + dloc;
            float aq[4], ak[4], av[4];
#pragma unroll
            for (int rr = 0; rr < 4; rr++) { aq[rr] = in_b[rq]; ak[rr] = in_b[H + rq]; av[rr] = in_b[2 * H + rq]; }
            for (int k = 0; k < H; ++k) {
                float wq = in_wT[k * 768 + rq];
                float wk = in_wT[k * 768 + 256 + rq];
                float wv = in_wT[k * 768 + 512 + rq];
#pragma unroll
                for (int rr = 0; rr < 4; rr++) {
                    float m = ml[iset + 8 * rr][k];
                    aq[rr] = fmaf(m, wq, aq[rr]); ak[rr] = fmaf(m, wk, ak[rr]); av[rr] = fmaf(m, wv, av[rr]);
                }
            }
#pragma unroll
            for (int rr = 0; rr < 4; rr++) { qh[iset + 8 * rr][dloc] = aq[rr]; kh[iset + 8 * rr][dloc] = ak[rr]; vh[iset + 8 * rr][dloc] = av[rr]; }
        }
        __syncthreads();
        {
            int i = tid >> 3;
            int j0 = (tid & 7) * 4;
            float a[4] = { 0.f, 0.f, 0.f, 0.f };
            for (int d = 0; d < DH; ++d) {
                float q = qh[i][d];
#pragma unroll
                for (int jj = 0; jj < 4; jj++) a[jj] = fmaf(q, kh[j0 + jj][d], a[jj]);
            }
#pragma unroll
            for (int jj = 0; jj < 4; jj++) sc[i][j0 + jj] = a[jj] * scale;
        }
        __syncthreads();
        if (tid < NS) {
            float mx = -1e30f;
            for (int j = 0; j < NS; j++) mx = fmaxf(mx, sc[tid][j]);
            float sm = 0.f, e[NS];
            for (int j = 0; j < NS; j++) { e[j] = __expf(sc[tid][j] - mx); sm += e[j]; }
            float inv = 1.f / sm;
            for (int j = 0; j < NS; j++) sc[tid][j] = e[j] * inv;
        }
        __syncthreads();
        {
            int i = tid >> 3;
            int d0 = (tid & 7) * 4;
            float a[4] = { 0.f, 0.f, 0.f, 0.f };
            for (int j = 0; j < NS; ++j) {
                float sv = sc[i][j];
#pragma unroll
                for (int dd = 0; dd < 4; dd++) a[dd] = fmaf(sv, vh[j][d0 + dd], a[dd]);
            }
#pragma unroll
            for (int dd = 0; dd < 4; dd++) buf[i][h * DH + d0 + dd] = a[dd];
        }
        __syncthreads();
    }

    {
        float acc32[NS];
        float ob = outp_b[tid];
#pragma unroll
        for (int t = 0; t < NS; t++) acc32[t] = ob;
        for (int k = 0; k < H; ++k) {
            float w = outp_wT[k * H + tid];
#pragma unroll
            for (int t = 0; t < NS; t++) acc32[t] = fmaf(buf[t][k], w, acc32[t]);
        }
#pragma unroll
        for (int t = 0; t < NS; t++) ml[t][tid] += acc32[t];
    }
    __syncthreads();

    float acc_o[NS];
    {
        float b2v = b2[tid];
#pragma unroll
        for (int t = 0; t < NS; t++) acc_o[t] = b2v;
    }
    for (int jc = 0; jc < 4; ++jc) {
        float hid[NS];
        {
            float b1v = b1[jc * H + tid];
#pragma unroll
            for (int t = 0; t < NS; t++) hid[t] = b1v;
            for (int k = 0; k < H; ++k) {
                float w = w1T[k * G4 + jc * H + tid];
#pragma unroll
                for (int t = 0; t < NS; t++) hid[t] = fmaf(ml[t][k], w, hid[t]);
            }
        }
        __syncthreads();
#pragma unroll
        for (int t = 0; t < NS; t++) buf[t][tid] = fmaxf(hid[t], 0.f);
        __syncthreads();
        for (int k = 0; k < H; ++k) {
            float w = w2T[(jc * H + k) * H + tid];
#pragma unroll
            for (int t = 0; t < NS; t++) acc_o[t] = fmaf(buf[t][k], w, acc_o[t]);
        }
        __syncthreads();
    }

    float p = 0.f;
#pragma unroll
    for (int t = 0; t < NS; t++) p += tanhf(ml[t][tid] + acc_o[t]);
    p *= (1.f / NS);
    v = p * fw[tid];
    for (int o = 32; o > 0; o >>= 1) v += __shfl_down(v, o);
    if ((tid & 63) == 0) red[tid >> 6] = v;
    __syncthreads();
    if (tid == 0) out[b] = red[0] + red[1] + red[2] + red[3] + fb[0];
}

// ---------------- host ----------------
extern "C" void kernel_launch(void* const* d_in, const int* in_sizes, int n_in,
                              void* d_out, int out_size, void* d_ws, size_t ws_size,
                              hipStream_t stream) {
    const float* x      = (const float*)d_in[0];
    const float* stw    = (const float*)d_in[1];
    const float* stb    = (const float*)d_in[2];
    const float* mtw    = (const float*)d_in[3];
    const float* mtb    = (const float*)d_in[4];
    const float* s_wih  = (const float*)d_in[5];
    const float* s_whh  = (const float*)d_in[6];
    const float* s_bih  = (const float*)d_in[7];
    const float* s_bhh  = (const float*)d_in[8];
    const float* m_wih  = (const float*)d_in[9];
    const float* m_whh  = (const float*)d_in[10];
    const float* m_bih  = (const float*)d_in[11];
    const float* m_bhh  = (const float*)d_in[12];
    const float* norm_w = (const float*)d_in[13];
    const float* norm_b = (const float*)d_in[14];
    const float* macro_w= (const float*)d_in[15];
    const float* in_w   = (const float*)d_in[16];
    const float* in_b   = (const float*)d_in[17];
    const float* outp_w = (const float*)d_in[18];
    const float* outp_b = (const float*)d_in[19];
    const float* w1     = (const float*)d_in[20];
    const float* b1     = (const float*)d_in[21];
    const float* w2     = (const float*)d_in[22];
    const float* b2     = (const float*)d_in[23];
    const float* fw     = (const float*)d_in[24];
    const float* fb     = (const float*)d_in[25];
    float* out = (float*)d_out;

    // workspace layout (256B-aligned blocks)
    size_t off = 0;
    auto alloc = [&](size_t bytes) { char* q = (char*)d_ws + off; off += (bytes + 255) & ~(size_t)255; return q; };
    _Float16* W16h  = (_Float16*)alloc((size_t)2 * 8 * 128 * 384 * 2);
    _Float16* W16l  = (_Float16*)alloc((size_t)2 * 8 * 128 * 256 * 2);
    float*    biasP = (float*)alloc((size_t)2 * 8 * 128 * 4);
    _Float16* trW16 = (_Float16*)alloc((size_t)256 * 128 * 2);
    _Float16* hG    = (_Float16*)alloc((size_t)32 * 2 * 2 * 16 * 256 * 2);            // 1 MB (hi only)
    unsigned int* flags = (unsigned int*)alloc((size_t)32 * 2 * 8 * 4 * 16 * 4);      // 128 KB, line-padded tags
    float*    ctx_s = (float*)alloc((size_t)B * H * 4);
    float*    ctx_m = (float*)alloc((size_t)B * H * 4);
    float*    in_wT = (float*)alloc((size_t)H * 768 * 4);
    float*    outp_wT = (float*)alloc((size_t)H * H * 4);
    float*    w1T   = (float*)alloc((size_t)H * G4 * 4);
    float*    w2T   = (float*)alloc((size_t)G4 * H * 4);
    _Float16* xtr16 = (_Float16*)alloc((size_t)2 * B * S * 128 * 2);                  // 64 MiB
    size_t off_before_hs = off;
    const size_t hs_elems = (size_t)2 * B * S * H;
    const size_t need_full = off_before_hs + hs_elems * sizeof(float) + (1u << 20);
    const bool f32hs = ws_size >= need_full;

    prep_kernel<<<128, 256, 0, stream>>>(s_wih, s_whh, s_bih, s_bhh,
                                         m_wih, m_whh, m_bih, m_bhh,
                                         stw, mtw, in_w, outp_w, w1, w2,
                                         W16h, W16l, biasP, trW16,
                                         in_wT, outp_wT, w1T, w2T);
    xtr_kernel<<<B, 256, 0, stream>>>(x, trW16, stb, mtb, xtr16);
    (void)hipMemsetAsync(flags, 0, (size_t)32 * 2 * 8 * 4 * 16 * 4, stream);

    if (f32hs) {
        float* hs = (float*)alloc(hs_elems * sizeof(float));
        lstm_mfma<float><<<256, 256, 0, stream>>>(W16h, W16l, biasP, xtr16, hs, hG, flags);
        attn_ctx_kernel<float><<<dim3(B, 2), 256, 0, stream>>>(hs, hs + hs_elems / 2, ctx_s, ctx_m);
    } else {
        _Float16* hs = (_Float16*)alloc(hs_elems * sizeof(_Float16));
        lstm_mfma<_Float16><<<256, 256, 0, stream>>>(W16h, W16l, biasP, xtr16, hs, hG, flags);
        attn_ctx_kernel<_Float16><<<dim3(B, 2), 256, 0, stream>>>(hs, hs + hs_elems / 2, ctx_s, ctx_m);
    }

    tail_kernel<<<B, 256, 0, stream>>>(ctx_s, ctx_m,
                                       norm_w, norm_b, macro_w,
                                       in_wT, in_b, outp_wT, outp_b,
                                       w1T, b1, w2T, b2, fw, fb, out);
}

// Round 14
// 1099.159 us; speedup vs baseline: 2.2388x; 1.9479x over previous
//
#include <hip/hip_runtime.h>
#include <hip/hip_bf16.h>
#include <math.h>

#define B 512
#define S 256
#define D 128
#define H 256
#define G4 1024
#define NS 32
#define NH 8
#define DH 32

typedef _Float16 half8 __attribute__((ext_vector_type(8)));
typedef _Float16 half2v __attribute__((ext_vector_type(2)));
typedef float f32x4 __attribute__((ext_vector_type(4)));

__device__ __forceinline__ float sigm(float v) { return 1.f / (1.f + __expf(-v)); }
__device__ __forceinline__ float tanh_fast(float x) { float e = __expf(2.f * x); return 1.f - 2.f / (e + 1.f); }
__device__ __forceinline__ float cvtf(float v) { return v; }
__device__ __forceinline__ float cvtf(_Float16 v) { return (float)v; }
__device__ __forceinline__ f32x4 mfma16(half8 a, half8 b, f32x4 c) {
    return __builtin_amdgcn_mfma_f32_16x16x32_f16(a, b, c, 0, 0, 0);
}

// ---------------- prep: lstm fp16 slices + MFMA-fragment-packed tail weights ----------------
// frag pack for GEMM [N][K]: dst[((nt*KS+ks)*64+ln)*8+q] = W[(nt*16+(ln&15))*K + ks*32+(ln>>4)*8+q]
__global__ void prep_kernel(const float* __restrict__ s_wih, const float* __restrict__ s_whh,
                            const float* __restrict__ s_bih, const float* __restrict__ s_bhh,
                            const float* __restrict__ m_wih, const float* __restrict__ m_whh,
                            const float* __restrict__ m_bih, const float* __restrict__ m_bhh,
                            const float* __restrict__ stw, const float* __restrict__ mtw,
                            const float* __restrict__ in_w, const float* __restrict__ outp_w,
                            const float* __restrict__ w1, const float* __restrict__ w2,
                            _Float16* __restrict__ W16h, _Float16* __restrict__ W16l,
                            float* __restrict__ biasP, _Float16* __restrict__ trW16,
                            _Float16* __restrict__ inWf,
                            _Float16* __restrict__ outWfh, _Float16* __restrict__ outWfl,
                            _Float16* __restrict__ w1fh, _Float16* __restrict__ w1fl,
                            _Float16* __restrict__ w2fh, _Float16* __restrict__ w2fl)
{
    int tid = blockIdx.x * blockDim.x + threadIdx.x;
    int stride = gridDim.x * blockDim.x;
    for (int i = tid; i < 2 * 8 * 128 * 384; i += stride) {
        int k = i % 384; int n = (i / 384) % 128; int c = (i / (384 * 128)) % 8; int L = i / (384 * 128 * 8);
        int row = (n >> 5) * 256 + c * 32 + (n & 31);
        const float* wih = L ? m_wih : s_wih;
        const float* whh = L ? m_whh : s_whh;
        float v = (k < 128) ? wih[row * 128 + k] : whh[row * 256 + (k - 128)];
        W16h[i] = (_Float16)v;
    }
    for (int i = tid; i < 2 * 8 * 128 * 256; i += stride) {
        int k = i % 256; int n = (i / 256) % 128; int c = (i / (256 * 128)) % 8; int L = i / (256 * 128 * 8);
        int row = (n >> 5) * 256 + c * 32 + (n & 31);
        const float* whh = L ? m_whh : s_whh;
        float v = whh[row * 256 + k];
        _Float16 hi = (_Float16)v;
        W16l[i] = (_Float16)(v - (float)hi);
    }
    for (int i = tid; i < 2 * 8 * 128; i += stride) {
        int n = i % 128; int c = (i / 128) % 8; int L = i / (128 * 8);
        int row = (n >> 5) * 256 + c * 32 + (n & 31);
        biasP[i] = L ? (m_bih[row] + m_bhh[row]) : (s_bih[row] + s_bhh[row]);
    }
    for (int i = tid; i < 256 * 128; i += stride) {
        int k = i % 128, n = i / 128;
        trW16[i] = (_Float16)(n < 128 ? stw[n * 128 + k] : mtw[(n - 128) * 128 + k]);
    }
    // in_proj: N=768 K=256 KS=8, single fp16
    for (int i = tid; i < 768 * 256; i += stride) {
        int q = i & 7, ln = (i >> 3) & 63, rest = i >> 9;
        int ks = rest & 7, nt = rest >> 3;
        int n = nt * 16 + (ln & 15), k = ks * 32 + (ln >> 4) * 8 + q;
        inWf[i] = (_Float16)in_w[n * 256 + k];
    }
    // out_proj: N=256 K=256 KS=8, hi/lo
    for (int i = tid; i < 256 * 256; i += stride) {
        int q = i & 7, ln = (i >> 3) & 63, rest = i >> 9;
        int ks = rest & 7, nt = rest >> 3;
        int n = nt * 16 + (ln & 15), k = ks * 32 + (ln >> 4) * 8 + q;
        float v = outp_w[n * 256 + k];
        _Float16 hi = (_Float16)v;
        outWfh[i] = hi; outWfl[i] = (_Float16)(v - (float)hi);
    }
    // w1: N=1024 K=256 KS=8, hi/lo
    for (int i = tid; i < 1024 * 256; i += stride) {
        int q = i & 7, ln = (i >> 3) & 63, rest = i >> 9;
        int ks = rest & 7, nt = rest >> 3;
        int n = nt * 16 + (ln & 15), k = ks * 32 + (ln >> 4) * 8 + q;
        float v = w1[n * 256 + k];
        _Float16 hi = (_Float16)v;
        w1fh[i] = hi; w1fl[i] = (_Float16)(v - (float)hi);
    }
    // w2: N=256 K=1024 KS=32, hi/lo
    for (int i = tid; i < 256 * 1024; i += stride) {
        int q = i & 7, ln = (i >> 3) & 63, rest = i >> 9;
        int ks = rest & 31, nt = rest >> 5;
        int n = nt * 16 + (ln & 15), k = ks * 32 + (ln >> 4) * 8 + q;
        float v = w2[n * 1024 + k];
        _Float16 hi = (_Float16)v;
        w2fh[i] = hi; w2fl[i] = (_Float16)(v - (float)hi);
    }
}

// ---------------- xtr ----------------
__global__ __launch_bounds__(256, 1) void xtr_kernel(const float* __restrict__ x,
        const _Float16* __restrict__ trW16,
        const float* __restrict__ stb, const float* __restrict__ mtb,
        _Float16* __restrict__ xtr16)
{
    const int b = blockIdx.x;
    const int tid = threadIdx.x;
    const int w = tid >> 6, l = tid & 63, l15 = l & 15, l4 = l >> 4;

    __shared__ _Float16 xa[128 * 128];

    half8 bw[4][4];
#pragma unroll
    for (int kk = 0; kk < 4; kk++)
#pragma unroll
        for (int ni = 0; ni < 4; ni++)
            bw[kk][ni] = *(const half8*)(trW16 + (w * 64 + ni * 16 + l15) * 128 + kk * 32 + l4 * 8);
    float tb[4];
#pragma unroll
    for (int ni = 0; ni < 4; ni++) { int d = w * 64 + ni * 16 + l15; tb[ni] = d < 128 ? stb[d] : mtb[d - 128]; }

    for (int h2 = 0; h2 < 2; ++h2) {
        {
            int trow = tid >> 1, seg = tid & 1;
            const float* src = x + ((size_t)b * S + h2 * 128 + trow) * 128 + seg * 64;
            int swz = (trow & 7) << 4;
#pragma unroll
            for (int q8 = 0; q8 < 8; q8++) {
                float4 f0 = *(const float4*)(src + q8 * 8);
                float4 f1 = *(const float4*)(src + q8 * 8 + 4);
                half8 hv = { (_Float16)f0.x, (_Float16)f0.y, (_Float16)f0.z, (_Float16)f0.w,
                             (_Float16)f1.x, (_Float16)f1.y, (_Float16)f1.z, (_Float16)f1.w };
                int byte = ((seg * 64 + q8 * 8) * 2) ^ swz;
                *(half8*)((char*)(xa + trow * 128) + byte) = hv;
            }
        }
        __syncthreads();
        for (int mt = 0; mt < 8; ++mt) {
            int row = mt * 16 + l15;
            int swz = (row & 7) << 4;
            half8 af[4];
#pragma unroll
            for (int kk = 0; kk < 4; kk++) {
                int byte = ((kk * 32 + l4 * 8) * 2) ^ swz;
                af[kk] = *(const half8*)((const char*)(xa + row * 128) + byte);
            }
            f32x4 acc[4];
#pragma unroll
            for (int ni = 0; ni < 4; ni++) acc[ni] = (f32x4){ tb[ni], tb[ni], tb[ni], tb[ni] };
#pragma unroll
            for (int kk = 0; kk < 4; kk++)
#pragma unroll
                for (int ni = 0; ni < 4; ni++)
                    acc[ni] = mfma16(af[kk], bw[kk][ni], acc[ni]);
#pragma unroll
            for (int ni = 0; ni < 4; ni++) {
                int d = w * 64 + ni * 16 + l15;
                int Ls = d >> 7, dl = d & 127;
#pragma unroll
                for (int r = 0; r < 4; r++) {
                    int t = h2 * 128 + mt * 16 + l4 * 4 + r;
                    xtr16[(((size_t)Ls * B + b) * S + t) * 128 + dl] = (_Float16)tanh_fast(acc[ni][r]);
                }
            }
        }
        __syncthreads();
    }
}

// ---------------- persistent MFMA LSTM (unchanged from R13) ----------------
#define LSTM_GATES(c)                                                                   \
    {                                                                                   \
        f32x4 a0 = (f32x4){ bn[0], bn[0], bn[0], bn[0] };                               \
        f32x4 a1 = (f32x4){ bn[1], bn[1], bn[1], bn[1] };                               \
        const char* ahBase = (const char*)(&Ah[c][0] + l15 * 384);                      \
        _Pragma("unroll")                                                               \
        for (int kk = 0; kk < 4; kk++) {                                                \
            half8 ah = *(const half8*)(ahBase + (((kk * 32 + l4 * 8) * 2) ^ aswz));     \
            a0 = mfma16(ah, bwh[kk][0], a0);                                            \
            a1 = mfma16(ah, bwh[kk][1], a1);                                            \
        }                                                                               \
        _Pragma("unroll")                                                               \
        for (int kk = 4; kk < 12; kk++) {                                               \
            int jb = ((kk - 4) * 32 + l4 * 8) * 2;                                      \
            half8 ah = *(const half8*)(ahBase + 256 + (jb ^ aswz));                     \
            a0 = mfma16(ah, bwh[kk][0], a0);                                            \
            a0 = mfma16(ah, bwlo[kk - 4][0], a0);                                       \
            a1 = mfma16(ah, bwh[kk][1], a1);                                            \
            a1 = mfma16(ah, bwlo[kk - 4][1], a1);                                       \
        }                                                                               \
        _Pragma("unroll")                                                               \
        for (int q = 0; q < 4; q++) {                                                   \
            gl[c][l4 * 4 + q][w * 32 + l15] = a0[q];                                    \
            gl[c][l4 * 4 + q][w * 32 + 16 + l15] = a1[q];                               \
        }                                                                               \
    }

#define LSTM_PW(c)                                                                      \
    {                                                                                   \
        int j2 = seg * 2;                                                               \
        float2 iv = *(const float2*)&gl[c][b16][0 + j2];                                \
        float2 fv = *(const float2*)&gl[c][b16][32 + j2];                               \
        float2 gv = *(const float2*)&gl[c][b16][64 + j2];                               \
        float2 ov = *(const float2*)&gl[c][b16][96 + j2];                               \
        float iq[2] = { iv.x, iv.y }, fq[2] = { fv.x, fv.y };                           \
        float gq[2] = { gv.x, gv.y }, oq[2] = { ov.x, ov.y };                           \
        float hv[2]; _Float16 hh[2];                                                    \
        _Pragma("unroll")                                                               \
        for (int q = 0; q < 2; q++) {                                                   \
            float cc = sigm(fq[q]) * cst[c][q] + sigm(iq[q]) * tanh_fast(gq[q]);        \
            cst[c][q] = cc;                                                             \
            hv[q] = sigm(oq[q]) * tanh_fast(cc);                                        \
            hh[q] = (_Float16)hv[q];                                                    \
        }                                                                               \
        if (more) {                                                                     \
            _Float16* dst = hG + ((size_t)(r * 2 + (c)) * 2 + par) * 16 * 256 + b16 * 256 + sC * 32 + j2; \
            half2v phi = { hh[0], hh[1] };                                              \
            asm volatile("global_store_dword %0, %1, off sc0 sc1" :: "v"(dst), "v"(phi) : "memory"); \
        }                                                                               \
        size_t hidx = (((size_t)L * B + b0 + (c) * 16 + b16) * S + t) * H + sC * 32 + j2; \
        if constexpr (sizeof(HT) == 4) {                                                \
            float2 hv2 = make_float2(hv[0], hv[1]);                                     \
            asm volatile("global_store_dwordx2 %0, %1, off" :: "v"((float*)hs + hidx), "v"(hv2) : "memory"); \
        } else {                                                                        \
            half2v ph = { hh[0], hh[1] };                                               \
            asm volatile("global_store_dword %0, %1, off" :: "v"((_Float16*)hs + hidx), "v"(ph) : "memory"); \
        }                                                                               \
    }

template<typename HT>
__global__ __launch_bounds__(256, 1) void lstm_mfma(
    const _Float16* __restrict__ W16h, const _Float16* __restrict__ W16l,
    const float* __restrict__ biasP,
    const _Float16* __restrict__ xtr16,
    HT* __restrict__ hs, _Float16* __restrict__ hG, unsigned int* __restrict__ flags)
{
    const int bid = blockIdx.x;
    const int sC = bid >> 5;
    const int r  = bid & 31;
    const int L  = r >> 4;
    const int btp = r & 15;
    const int b0 = btp * 32;
    const int tid = threadIdx.x;
    const int w = tid >> 6, l = tid & 63, l15 = l & 15, l4 = l >> 4;

    __shared__ _Float16 Ah[2][16 * 384];
    __shared__ float gl[2][16][132];

    for (int i = tid; i < 2 * 16 * 384 * 2 / 16; i += 256) ((int4*)&Ah[0][0])[i] = make_int4(0, 0, 0, 0);

    const size_t wbh = ((size_t)(L * 8 + sC) * 128) * 384;
    const size_t wbl = ((size_t)(L * 8 + sC) * 128) * 256;
    half8 bwh[12][2], bwlo[8][2];
#pragma unroll
    for (int kk = 0; kk < 12; kk++)
#pragma unroll
        for (int ni = 0; ni < 2; ni++)
            bwh[kk][ni] = *(const half8*)(W16h + wbh + (size_t)(w * 32 + ni * 16 + l15) * 384 + kk * 32 + l4 * 8);
#pragma unroll
    for (int kk = 0; kk < 8; kk++)
#pragma unroll
        for (int ni = 0; ni < 2; ni++)
            bwlo[kk][ni] = *(const half8*)(W16l + wbl + (size_t)(w * 32 + ni * 16 + l15) * 256 + kk * 32 + l4 * 8);
    float bn[2];
#pragma unroll
    for (int ni = 0; ni < 2; ni++) bn[ni] = biasP[(L * 8 + sC) * 128 + w * 32 + ni * 16 + l15];

    const int b16 = tid >> 4;
    const int seg = tid & 15;
    const int bswz = (b16 & 7) << 4;
    const int aswz = (l15 & 7) << 4;

#pragma unroll
    for (int c = 0; c < 2; c++) {
        const _Float16* src = xtr16 + (((size_t)L * B + b0 + c * 16 + b16) * S + 0) * 128 + seg * 8;
        half8 v0 = *(const half8*)src;
        *(half8*)((char*)(&Ah[c][0] + b16 * 384) + ((seg * 16) ^ bswz)) = v0;
    }
    float cst[2][2] = { { 0.f, 0.f }, { 0.f, 0.f } };
    half8 xp[2];
    half8 cvh[2][2];
    unsigned int* wf0 = flags + (((size_t)(r * 2 + 0) * 8 + sC) * 4 + w) * 16;
    unsigned int* wf1 = flags + (((size_t)(r * 2 + 1) * 8 + sC) * 4 + w) * 16;
    const unsigned int* pf0 = flags + (((size_t)(r * 2 + 0) * 8 + (seg >> 1)) * 4 + w) * 16;
    const unsigned int* pf1 = flags + (((size_t)(r * 2 + 1) * 8 + (seg >> 1)) * 4 + w) * 16;
    __syncthreads();

    for (int t = 0; t < S; ++t) {
        const int par = t & 1;
        const bool more = (t < S - 1);

        LSTM_GATES(0)
        asm volatile("s_waitcnt lgkmcnt(0)" ::: "memory");
        __builtin_amdgcn_s_barrier();

        LSTM_PW(0)
        LSTM_GATES(1)
        asm volatile("s_waitcnt lgkmcnt(0)" ::: "memory");
        __builtin_amdgcn_s_barrier();

        LSTM_PW(1)

        if (more) {
            unsigned int tagv = (unsigned int)(t + 1);
            asm volatile("s_waitcnt vmcnt(3)" ::: "memory");
            if (l == 0)
                asm volatile("global_store_dword %0, %1, off sc0 sc1" :: "v"(wf0), "v"(tagv) : "memory");
            asm volatile("s_waitcnt vmcnt(1)" ::: "memory");
            if (l == 0)
                asm volatile("global_store_dword %0, %1, off sc0 sc1" :: "v"(wf1), "v"(tagv) : "memory");
#pragma unroll
            for (int c = 0; c < 2; c++) {
                const _Float16* src = xtr16 + (((size_t)L * B + b0 + c * 16 + b16) * S + (t + 1)) * 128 + seg * 8;
                asm volatile("global_load_dwordx4 %0, %1, off" : "=v"(xp[c]) : "v"(src) : "memory");
            }
            {
                unsigned int v0, v1;
                while (true) {
                    asm volatile("global_load_dword %0, %2, off sc0 sc1\n\t"
                                 "global_load_dword %1, %3, off sc0 sc1\n\t"
                                 "s_waitcnt vmcnt(0)"
                                 : "=v"(v0), "=v"(v1) : "v"(pf0), "v"(pf1) : "memory");
                    if (v0 > (unsigned int)t && v1 > (unsigned int)t) break;
                    __builtin_amdgcn_s_sleep(1);
                }
            }
            {
                const _Float16* s0 = hG + ((size_t)(r * 2 + 0) * 2 + par) * 16 * 256 + b16 * 256 + seg * 16;
                const _Float16* s1 = hG + ((size_t)(r * 2 + 1) * 2 + par) * 16 * 256 + b16 * 256 + seg * 16;
                asm volatile("global_load_dwordx4 %0, %1, off sc0 sc1" : "=v"(cvh[0][0]) : "v"(s0) : "memory");
                asm volatile("global_load_dwordx4 %0, %1, off sc0 sc1" : "=v"(cvh[0][1]) : "v"(s0 + 8) : "memory");
                asm volatile("global_load_dwordx4 %0, %1, off sc0 sc1" : "=v"(cvh[1][0]) : "v"(s1) : "memory");
                asm volatile("global_load_dwordx4 %0, %1, off sc0 sc1" : "=v"(cvh[1][1]) : "v"(s1 + 8) : "memory");
                asm volatile("s_waitcnt vmcnt(0)" ::: "memory");
                __builtin_amdgcn_sched_barrier(0);
            }
#pragma unroll
            for (int c = 0; c < 2; c++) {
#pragma unroll
                for (int u = 0; u < 2; u++) {
                    int jb = (seg * 16 + u * 8) * 2;
                    *(half8*)((char*)(&Ah[c][0] + b16 * 384) + 256 + (jb ^ bswz)) = cvh[c][u];
                }
                *(half8*)((char*)(&Ah[c][0] + b16 * 384) + ((seg * 16) ^ bswz)) = xp[c];
            }
            asm volatile("s_waitcnt lgkmcnt(0)" ::: "memory");
            __builtin_amdgcn_s_barrier();
        }
    }
}

// ---------------- attention context (unchanged) ----------------
template<typename HT>
__global__ __launch_bounds__(256) void attn_ctx_kernel(const HT* __restrict__ hs_s, const HT* __restrict__ hs_m,
                                                       float* __restrict__ ctx_s, float* __restrict__ ctx_m)
{
    const int b = blockIdx.x;
    const int L = blockIdx.y;
    const HT* hsb = (L ? hs_m : hs_s) + (size_t)b * S * H;
    float* ctx = (L ? ctx_m : ctx_s) + b * H;
    const int tid = threadIdx.x;
    const int wv = tid >> 6, l = tid & 63;

    __shared__ float hlast[H];
    __shared__ float score[S];
    __shared__ float dist[S];
    __shared__ float red[4];

    hlast[tid] = cvtf(hsb[(size_t)(S - 1) * H + tid]);
    __syncthreads();

    const int segl = l & 15;
    for (int it = 0; it < 16; ++it) {
        int row = it * 16 + wv * 4 + (l >> 4);
        float s = 0.f;
        if constexpr (sizeof(HT) == 2) {
            const half8* p = (const half8*)(hsb + (size_t)row * H + segl * 16);
#pragma unroll
            for (int u = 0; u < 2; u++) {
                half8 v = p[u];
#pragma unroll
                for (int j = 0; j < 8; j++) s = fmaf((float)v[j], hlast[segl * 16 + u * 8 + j], s);
            }
        } else {
            const float4* p = (const float4*)(hsb + (size_t)row * H + segl * 16);
#pragma unroll
            for (int u = 0; u < 4; u++) {
                float4 v = p[u];
                s = fmaf(v.x, hlast[segl * 16 + u * 4 + 0], s);
                s = fmaf(v.y, hlast[segl * 16 + u * 4 + 1], s);
                s = fmaf(v.z, hlast[segl * 16 + u * 4 + 2], s);
                s = fmaf(v.w, hlast[segl * 16 + u * 4 + 3], s);
            }
        }
        s += __shfl_xor(s, 1); s += __shfl_xor(s, 2); s += __shfl_xor(s, 4); s += __shfl_xor(s, 8);
        if (segl == 0) score[row] = s;
    }
    __syncthreads();

    float sct = score[tid];
    float v = sct;
    for (int o = 32; o > 0; o >>= 1) v += __shfl_down(v, o);
    if ((tid & 63) == 0) red[tid >> 6] = v;
    __syncthreads();
    float denom = red[0] + red[1] + red[2] + red[3];
    dist[tid] = sct / denom;
    __syncthreads();

    float acc = 0.f;
    for (int t = 0; t < S; ++t) acc = fmaf(dist[t], cvtf(hsb[(size_t)t * H + tid]), acc);
    ctx[tid] = acc;
}

// ---------------- MFMA tail ----------------
__device__ __forceinline__ void load_afrag(const _Float16* buf, int l15, int l4, half8 dst[2][8]) {
#pragma unroll
    for (int m = 0; m < 2; m++)
#pragma unroll
        for (int ks2 = 0; ks2 < 8; ks2++) {
            int row = m * 16 + l15;
            dst[m][ks2] = *(const half8*)((const char*)buf + row * 512 + (((ks2 * 32 + l4 * 8) * 2) ^ ((row & 7) << 4)));
        }
}

__global__ __launch_bounds__(256, 1) void tail_mfma(
    const float* __restrict__ ctx_s, const float* __restrict__ ctx_m,
    const float* __restrict__ norm_w, const float* __restrict__ norm_b,
    const float* __restrict__ macro_w,
    const _Float16* __restrict__ inWf, const float* __restrict__ in_b,
    const _Float16* __restrict__ outWfh, const _Float16* __restrict__ outWfl, const float* __restrict__ outp_b,
    const _Float16* __restrict__ w1fh, const _Float16* __restrict__ w1fl, const float* __restrict__ b1,
    const _Float16* __restrict__ w2fh, const _Float16* __restrict__ w2fl, const float* __restrict__ b2,
    const float* __restrict__ fw, const float* __restrict__ fb,
    float* __restrict__ out)
{
    const int b = blockIdx.x;
    const int tid = threadIdx.x;
    const int w = tid >> 6, l = tid & 63, l15 = l & 15, l4 = l >> 4;

    __shared__ _Float16 mlh[32 * 256];   // ml hi -> later h1 hi
    __shared__ _Float16 mll[32 * 256];   // ml lo -> later h1 lo
    __shared__ _Float16 qs[32 * 256];    // q     -> later hidden hi
    __shared__ _Float16 kss[32 * 256];   // k     -> later hidden lo
    __shared__ _Float16 vT[256 * 40];    // v transposed, padded rows
    __shared__ _Float16 att[32 * 256];   // attn concat
    __shared__ float scf[4][32][36];
    __shared__ _Float16 attw[4][32 * 40];
    __shared__ float redt[8];

    // ---- norm -> ml (hi/lo, swizzled) ----
    float cs = ctx_s[b * H + tid];
    float v = cs;
    for (int o = 32; o > 0; o >>= 1) v += __shfl_down(v, o);
    if ((tid & 63) == 0) redt[tid >> 6] = v;
    __syncthreads();
    float mean = (redt[0] + redt[1] + redt[2] + redt[3]) * (1.f / H);
    float dv = cs - mean;
    __syncthreads();
    v = dv * dv;
    for (int o = 32; o > 0; o >>= 1) v += __shfl_down(v, o);
    if ((tid & 63) == 0) redt[tid >> 6] = v;
    __syncthreads();
    float stdv = sqrtf((redt[0] + redt[1] + redt[2] + redt[3]) * (1.f / (H - 1))) + 1e-8f;
    float z = dv / stdv;
    float cm = ctx_m[b * H + tid];
    float mwv = macro_w[0];
    for (int n = 0; n < NS; ++n) {
        float mlv = norm_w[n * H + tid] * z + norm_b[n * H + tid] + mwv * cm;
        _Float16 hi = (_Float16)mlv;
        _Float16 lo = (_Float16)(mlv - (float)hi);
        int byte = n * 512 + ((tid * 2) ^ ((n & 7) << 4));
        *(_Float16*)((char*)mlh + byte) = hi;
        *(_Float16*)((char*)mll + byte) = lo;
    }
    __syncthreads();

    // ---- in_proj (A=ml hi/lo, W single fp16): wave w -> n in [w*192, w*192+192) ----
    {
        half8 amh[2][8], aml[2][8];
        load_afrag(mlh, l15, l4, amh);
        load_afrag(mll, l15, l4, aml);
        for (int i = 0; i < 12; i++) {
            int nt = w * 12 + i;
            int nb = nt * 16;
            float bias = in_b[nb + l15];
            f32x4 acc[2];
            acc[0] = (f32x4){ bias, bias, bias, bias };
            acc[1] = acc[0];
            const _Float16* bp = inWf + (size_t)nt * 8 * 512 + l * 8;
#pragma unroll
            for (int ks2 = 0; ks2 < 8; ks2++) {
                half8 bf = *(const half8*)(bp + ks2 * 512);
                acc[0] = mfma16(amh[0][ks2], bf, acc[0]);
                acc[0] = mfma16(aml[0][ks2], bf, acc[0]);
                acc[1] = mfma16(amh[1][ks2], bf, acc[1]);
                acc[1] = mfma16(aml[1][ks2], bf, acc[1]);
            }
#pragma unroll
            for (int m = 0; m < 2; m++)
#pragma unroll
                for (int qr = 0; qr < 4; qr++) {
                    int row = m * 16 + l4 * 4 + qr;
                    int col = nb + l15;
                    _Float16 hv = (_Float16)acc[m][qr];
                    if (col < 256) {
                        *(_Float16*)((char*)qs + row * 512 + ((col * 2) ^ ((row & 7) << 4))) = hv;
                    } else if (col < 512) {
                        int c2 = col - 256;
                        *(_Float16*)((char*)kss + row * 512 + ((c2 * 2) ^ ((row & 7) << 4))) = hv;
                    } else {
                        int dvi = col - 512;
                        *(_Float16*)((char*)vT + dvi * 80 + row * 2) = hv;
                    }
                }
        }
    }
    __syncthreads();

    // ---- attention: 2 heads per wave ----
    const float scale = 0.17677669529663687f;
    for (int hh = 0; hh < 2; hh++) {
        int hD = w * 2 + hh;
        // scores
        half8 aq[2], bk[2];
#pragma unroll
        for (int m = 0; m < 2; m++) {
            int row = m * 16 + l15;
            aq[m] = *(const half8*)((const char*)qs + row * 512 + (((hD * 32 + l4 * 8) * 2) ^ ((row & 7) << 4)));
            bk[m] = *(const half8*)((const char*)kss + row * 512 + (((hD * 32 + l4 * 8) * 2) ^ ((row & 7) << 4)));
        }
        f32x4 sacc[2][2];
#pragma unroll
        for (int m = 0; m < 2; m++)
#pragma unroll
            for (int n = 0; n < 2; n++) {
                sacc[m][n] = (f32x4){ 0.f, 0.f, 0.f, 0.f };
                sacc[m][n] = mfma16(aq[m], bk[n], sacc[m][n]);
            }
#pragma unroll
        for (int m = 0; m < 2; m++)
#pragma unroll
            for (int n = 0; n < 2; n++)
#pragma unroll
                for (int qr = 0; qr < 4; qr++)
                    scf[w][m * 16 + l4 * 4 + qr][n * 16 + l15] = sacc[m][n][qr];
        asm volatile("s_waitcnt lgkmcnt(0)" ::: "memory");
        __builtin_amdgcn_sched_barrier(0);
        // softmax rows (lanes 0..31, row = l)
        if (l < 32) {
            float mx = -1e30f;
            float e[32];
#pragma unroll 8
            for (int j = 0; j < 32; j++) { e[j] = scf[w][l][j] * scale; mx = fmaxf(mx, e[j]); }
            float sm = 0.f;
#pragma unroll 8
            for (int j = 0; j < 32; j++) { e[j] = __expf(e[j] - mx); sm += e[j]; }
            float inv = 1.f / sm;
#pragma unroll 8
            for (int j = 0; j < 32; j++) attw[w][l * 40 + j] = (_Float16)(e[j] * inv);
        }
        asm volatile("s_waitcnt lgkmcnt(0)" ::: "memory");
        __builtin_amdgcn_sched_barrier(0);
        // PV
        half8 aA[2], bv[2];
#pragma unroll
        for (int m = 0; m < 2; m++)
            aA[m] = *(const half8*)((const char*)attw[w] + (m * 16 + l15) * 80 + l4 * 16);
#pragma unroll
        for (int n = 0; n < 2; n++)
            bv[n] = *(const half8*)((const char*)vT + (hD * 32 + n * 16 + l15) * 80 + l4 * 16);
        f32x4 pacc[2][2];
#pragma unroll
        for (int m = 0; m < 2; m++)
#pragma unroll
            for (int n = 0; n < 2; n++) {
                pacc[m][n] = (f32x4){ 0.f, 0.f, 0.f, 0.f };
                pacc[m][n] = mfma16(aA[m], bv[n], pacc[m][n]);
            }
#pragma unroll
        for (int m = 0; m < 2; m++)
#pragma unroll
            for (int n = 0; n < 2; n++)
#pragma unroll
                for (int qr = 0; qr < 4; qr++) {
                    int row = m * 16 + l4 * 4 + qr;
                    int col = hD * 32 + n * 16 + l15;
                    *(_Float16*)((char*)att + row * 512 + ((col * 2) ^ ((row & 7) << 4))) = (_Float16)pacc[m][n][qr];
                }
        asm volatile("s_waitcnt lgkmcnt(0)" ::: "memory");
    }
    __syncthreads();

    // ---- out_proj + residual -> h1 (overwrite mlh/mll) ----
    {
        half8 aat[2][8];
        load_afrag(att, l15, l4, aat);
        for (int i = 0; i < 4; i++) {
            int nt = w * 4 + i;
            int nb = nt * 16;
            float bias = outp_b[nb + l15];
            f32x4 acc[2];
            acc[0] = (f32x4){ bias, bias, bias, bias };
            acc[1] = acc[0];
            const _Float16* bph = outWfh + (size_t)nt * 8 * 512 + l * 8;
            const _Float16* bpl = outWfl + (size_t)nt * 8 * 512 + l * 8;
#pragma unroll
            for (int ks2 = 0; ks2 < 8; ks2++) {
                half8 bh = *(const half8*)(bph + ks2 * 512);
                half8 bl = *(const half8*)(bpl + ks2 * 512);
#pragma unroll
                for (int m = 0; m < 2; m++) {
                    acc[m] = mfma16(aat[m][ks2], bh, acc[m]);
                    acc[m] = mfma16(aat[m][ks2], bl, acc[m]);
                }
            }
#pragma unroll
            for (int m = 0; m < 2; m++)
#pragma unroll
                for (int qr = 0; qr < 4; qr++) {
                    int row = m * 16 + l4 * 4 + qr;
                    int col = nb + l15;
                    int byte = row * 512 + ((col * 2) ^ ((row & 7) << 4));
                    float mlf = (float)*(_Float16*)((char*)mlh + byte) + (float)*(_Float16*)((char*)mll + byte);
                    float h1 = mlf + acc[m][qr];
                    _Float16 hi = (_Float16)h1;
                    *(_Float16*)((char*)mlh + byte) = hi;
                    *(_Float16*)((char*)mll + byte) = (_Float16)(h1 - (float)hi);
                }
        }
    }
    __syncthreads();

    // ---- MLP: 4 chunks of 256 hidden; w2 accumulates in fragments ----
    f32x4 oacc[2][4];
#pragma unroll
    for (int m = 0; m < 2; m++)
#pragma unroll
        for (int i = 0; i < 4; i++) {
            float bias = b2[w * 64 + i * 16 + l15];
            oacc[m][i] = (f32x4){ bias, bias, bias, bias };
        }
    for (int jc = 0; jc < 4; jc++) {
        {
            half8 ah1h[2][8], ah1l[2][8];
            load_afrag(mlh, l15, l4, ah1h);
            load_afrag(mll, l15, l4, ah1l);
            for (int i = 0; i < 4; i++) {
                int ntg = jc * 16 + w * 4 + i;
                float bias = b1[ntg * 16 + l15];
                f32x4 hacc[2];
                hacc[0] = (f32x4){ bias, bias, bias, bias };
                hacc[1] = hacc[0];
                const _Float16* bph = w1fh + (size_t)ntg * 8 * 512 + l * 8;
                const _Float16* bpl = w1fl + (size_t)ntg * 8 * 512 + l * 8;
#pragma unroll
                for (int ks2 = 0; ks2 < 8; ks2++) {
                    half8 bh = *(const half8*)(bph + ks2 * 512);
                    half8 bl = *(const half8*)(bpl + ks2 * 512);
#pragma unroll
                    for (int m = 0; m < 2; m++) {
                        hacc[m] = mfma16(ah1h[m][ks2], bh, hacc[m]);
                        hacc[m] = mfma16(ah1h[m][ks2], bl, hacc[m]);
                        hacc[m] = mfma16(ah1l[m][ks2], bh, hacc[m]);
                    }
                }
#pragma unroll
                for (int m = 0; m < 2; m++)
#pragma unroll
                    for (int qr = 0; qr < 4; qr++) {
                        int row = m * 16 + l4 * 4 + qr;
                        int col = w * 64 + i * 16 + l15;
                        float hv = fmaxf(hacc[m][qr], 0.f);
                        _Float16 hi = (_Float16)hv;
                        int byte = row * 512 + ((col * 2) ^ ((row & 7) << 4));
                        *(_Float16*)((char*)qs + byte) = hi;
                        *(_Float16*)((char*)kss + byte) = (_Float16)(hv - (float)hi);
                    }
            }
        }
        __syncthreads();   // hidden chunk ready
        {
            half8 ahh[2][8], ahl[2][8];
            load_afrag(qs, l15, l4, ahh);
            load_afrag(kss, l15, l4, ahl);
            for (int i = 0; i < 4; i++) {
                int nt = w * 4 + i;
                const _Float16* bph = w2fh + ((size_t)nt * 32 + jc * 8) * 512 + l * 8;
                const _Float16* bpl = w2fl + ((size_t)nt * 32 + jc * 8) * 512 + l * 8;
#pragma unroll
                for (int ks2 = 0; ks2 < 8; ks2++) {
                    half8 bh = *(const half8*)(bph + ks2 * 512);
                    half8 bl = *(const half8*)(bpl + ks2 * 512);
#pragma unroll
                    for (int m = 0; m < 2; m++) {
                        oacc[m][i] = mfma16(ahh[m][ks2], bh, oacc[m][i]);
                        oacc[m][i] = mfma16(ahh[m][ks2], bl, oacc[m][i]);
                        oacc[m][i] = mfma16(ahl[m][ks2], bh, oacc[m][i]);
                    }
                }
            }
        }
        __syncthreads();   // before next chunk overwrites hidden
    }

    // ---- final: out = tanh(h1 + mlp_out), pool tokens, dot fw ----
    float part = 0.f;
    for (int i = 0; i < 4; i++) {
        float p = 0.f;
#pragma unroll
        for (int m = 0; m < 2; m++)
#pragma unroll
            for (int qr = 0; qr < 4; qr++) {
                int row = m * 16 + l4 * 4 + qr;
                int col = w * 64 + i * 16 + l15;
                int byte = row * 512 + ((col * 2) ^ ((row & 7) << 4));
                float h1f = (float)*(_Float16*)((char*)mlh + byte) + (float)*(_Float16*)((char*)mll + byte);
                p += tanhf(h1f + oacc[m][i][qr]);
            }
        p += __shfl_xor(p, 16);
        p += __shfl_xor(p, 32);
        part += p * fw[w * 64 + i * 16 + l15];
    }
    part += __shfl_xor(part, 1);
    part += __shfl_xor(part, 2);
    part += __shfl_xor(part, 4);
    part += __shfl_xor(part, 8);
    if (l == 0) redt[w] = part;
    __syncthreads();
    if (tid == 0) out[b] = (redt[0] + redt[1] + redt[2] + redt[3]) * (1.f / NS) + fb[0];
}

// ---------------- host ----------------
extern "C" void kernel_launch(void* const* d_in, const int* in_sizes, int n_in,
                              void* d_out, int out_size, void* d_ws, size_t ws_size,
                              hipStream_t stream) {
    const float* x      = (const float*)d_in[0];
    const float* stw    = (const float*)d_in[1];
    const float* stb    = (const float*)d_in[2];
    const float* mtw    = (const float*)d_in[3];
    const float* mtb    = (const float*)d_in[4];
    const float* s_wih  = (const float*)d_in[5];
    const float* s_whh  = (const float*)d_in[6];
    const float* s_bih  = (const float*)d_in[7];
    const float* s_bhh  = (const float*)d_in[8];
    const float* m_wih  = (const float*)d_in[9];
    const float* m_whh  = (const float*)d_in[10];
    const float* m_bih  = (const float*)d_in[11];
    const float* m_bhh  = (const float*)d_in[12];
    const float* norm_w = (const float*)d_in[13];
    const float* norm_b = (const float*)d_in[14];
    const float* macro_w= (const float*)d_in[15];
    const float* in_w   = (const float*)d_in[16];
    const float* in_b   = (const float*)d_in[17];
    const float* outp_w = (const float*)d_in[18];
    const float* outp_b = (const float*)d_in[19];
    const float* w1     = (const float*)d_in[20];
    const float* b1     = (const float*)d_in[21];
    const float* w2     = (const float*)d_in[22];
    const float* b2     = (const float*)d_in[23];
    const float* fw     = (const float*)d_in[24];
    const float* fb     = (const float*)d_in[25];
    float* out = (float*)d_out;

    size_t off = 0;
    auto alloc = [&](size_t bytes) { char* q = (char*)d_ws + off; off += (bytes + 255) & ~(size_t)255; return q; };
    _Float16* W16h  = (_Float16*)alloc((size_t)2 * 8 * 128 * 384 * 2);
    _Float16* W16l  = (_Float16*)alloc((size_t)2 * 8 * 128 * 256 * 2);
    float*    biasP = (float*)alloc((size_t)2 * 8 * 128 * 4);
    _Float16* trW16 = (_Float16*)alloc((size_t)256 * 128 * 2);
    _Float16* hG    = (_Float16*)alloc((size_t)32 * 2 * 2 * 16 * 256 * 2);
    unsigned int* flags = (unsigned int*)alloc((size_t)32 * 2 * 8 * 4 * 16 * 4);
    float*    ctx_s = (float*)alloc((size_t)B * H * 4);
    float*    ctx_m = (float*)alloc((size_t)B * H * 4);
    _Float16* inWf  = (_Float16*)alloc((size_t)768 * 256 * 2);
    _Float16* outWfh= (_Float16*)alloc((size_t)256 * 256 * 2);
    _Float16* outWfl= (_Float16*)alloc((size_t)256 * 256 * 2);
    _Float16* w1fh  = (_Float16*)alloc((size_t)1024 * 256 * 2);
    _Float16* w1fl  = (_Float16*)alloc((size_t)1024 * 256 * 2);
    _Float16* w2fh  = (_Float16*)alloc((size_t)256 * 1024 * 2);
    _Float16* w2fl  = (_Float16*)alloc((size_t)256 * 1024 * 2);
    _Float16* xtr16 = (_Float16*)alloc((size_t)2 * B * S * 128 * 2);
    size_t off_before_hs = off;
    const size_t hs_elems = (size_t)2 * B * S * H;
    const size_t need_full = off_before_hs + hs_elems * sizeof(float) + (1u << 20);
    const bool f32hs = ws_size >= need_full;

    prep_kernel<<<128, 256, 0, stream>>>(s_wih, s_whh, s_bih, s_bhh,
                                         m_wih, m_whh, m_bih, m_bhh,
                                         stw, mtw, in_w, outp_w, w1, w2,
                                         W16h, W16l, biasP, trW16,
                                         inWf, outWfh, outWfl, w1fh, w1fl, w2fh, w2fl);
    xtr_kernel<<<B, 256, 0, stream>>>(x, trW16, stb, mtb, xtr16);
    (void)hipMemsetAsync(flags, 0, (size_t)32 * 2 * 8 * 4 * 16 * 4, stream);

    if (f32hs) {
        float* hs = (float*)alloc(hs_elems * sizeof(float));
        lstm_mfma<float><<<256, 256, 0, stream>>>(W16h, W16l, biasP, xtr16, hs, hG, flags);
        attn_ctx_kernel<float><<<dim3(B, 2), 256, 0, stream>>>(hs, hs + hs_elems / 2, ctx_s, ctx_m);
    } else {
        _Float16* hs = (_Float16*)alloc(hs_elems * sizeof(_Float16));
        lstm_mfma<_Float16><<<256, 256, 0, stream>>>(W16h, W16l, biasP, xtr16, hs, hG, flags);
        attn_ctx_kernel<_Float16><<<dim3(B, 2), 256, 0, stream>>>(hs, hs + hs_elems / 2, ctx_s, ctx_m);
    }

    tail_mfma<<<B, 256, 0, stream>>>(ctx_s, ctx_m, norm_w, norm_b, macro_w,
                                     inWf, in_b, outWfh, outWfl, outp_b,
                                     w1fh, w1fl, b1, w2fh, w2fl, b2,
                                     fw, fb, out);
}